// Round 2
// baseline (393.073 us; speedup 1.0000x reference)
//
#include <hip/hip_runtime.h>
#include <stdint.h>

#define N_NODES 50000
#define N_EDGES 800000
// D_IN=128, H1=128, H2=64, C=2  — all tensors fp32

// ---------- 1. in-degree count ----------
__global__ void k_count(const int* __restrict__ dst, int* __restrict__ counts) {
    int e = blockIdx.x * 256 + threadIdx.x;
    if (e < N_EDGES) {
        int d = dst[e];
        if ((unsigned)d < N_NODES) atomicAdd(&counts[d], 1);
    }
}

// ---------- 2. dinv = rsqrt(deg+1) ----------
__global__ void k_dinv(const int* __restrict__ counts, float* __restrict__ dinv) {
    int i = blockIdx.x * 256 + threadIdx.x;
    if (i < N_NODES) dinv[i] = rsqrtf((float)counts[i] + 1.0f);
}

// ---------- 3a. per-block exclusive scan of counts ----------
__global__ void k_scan1(const int* __restrict__ counts, int* __restrict__ offs,
                        int* __restrict__ bsums) {
    int t = threadIdx.x, b = blockIdx.x;
    int idx = b * 256 + t;
    int c = (idx < N_NODES) ? counts[idx] : 0;
    int v = c;
    int lane = t & 63, w = t >> 6;
    #pragma unroll
    for (int off = 1; off < 64; off <<= 1) {
        int u = __shfl_up(v, off);
        if (lane >= off) v += u;
    }
    __shared__ int wt[4];
    if (lane == 63) wt[w] = v;
    __syncthreads();
    int base = 0;
    for (int j = 0; j < w; j++) base += wt[j];
    if (idx < N_NODES) offs[idx] = base + v - c;
    if (t == 255) bsums[b] = base + v;
}

// ---------- 3b. exclusive scan of block sums (nb <= 256, one block) ----------
__global__ void k_scan2(int* __restrict__ bsums, int nb) {
    int t = threadIdx.x;
    int c = (t < nb) ? bsums[t] : 0;
    int v = c;
    int lane = t & 63, w = t >> 6;
    #pragma unroll
    for (int off = 1; off < 64; off <<= 1) {
        int u = __shfl_up(v, off);
        if (lane >= off) v += u;
    }
    __shared__ int wt[4];
    if (lane == 63) wt[w] = v;
    __syncthreads();
    int base = 0;
    for (int j = 0; j < w; j++) base += wt[j];
    if (t < nb) bsums[t] = base + v - c;   // exclusive prefix
}

// ---------- 3c. add block bases ----------
__global__ void k_scan3(int* __restrict__ offs, const int* __restrict__ bsums) {
    int idx = blockIdx.x * 256 + threadIdx.x;
    if (idx < N_NODES) offs[idx] += bsums[idx >> 8];
}

// ---------- 4. scatter edges into CSR (grouped by dst) ----------
__global__ void k_scatter(const int* __restrict__ src, const int* __restrict__ dst,
                          const int* __restrict__ offs, int* __restrict__ cursor,
                          const float* __restrict__ dinv,
                          int* __restrict__ csr_s, float* __restrict__ csr_c) {
    int e = blockIdx.x * 256 + threadIdx.x;
    if (e >= N_EDGES) return;
    int s = src[e], d = dst[e];
    if ((unsigned)s >= N_NODES || (unsigned)d >= N_NODES) return;
    int pos = offs[d] + atomicAdd(&cursor[d], 1);
    csr_s[pos] = s;
    csr_c[pos] = dinv[s] * dinv[d];
}

// ---------- 5. GEMM1: h1[50000,128] = x[50000,128] @ W1[128,128] ----------
__global__ __launch_bounds__(256) void k_gemm1(const float* __restrict__ x,
                                               const float* __restrict__ W1,
                                               float* __restrict__ h1) {
    __shared__ float Wf[64 * 128];  // 32 KB: K-half of W1, row-major [k][n]
    __shared__ float xT[64 * 32];   // 8 KB: xT[k][r], transposed 32-row tile
    int t = threadIdx.x;
    int row0 = blockIdx.x * 32;
    int tx = t & 31, ty = t >> 5;   // cols 4*tx (0..127), rows 4*ty (0..31)
    float acc[4][4] = {};
    for (int kh = 0; kh < 2; kh++) {
        int kbase = kh * 64;
        // stage W half: 64*128 floats = 2048 float4s
        for (int c = t; c < 2048; c += 256) {
            *(float4*)&Wf[c * 4] = *(const float4*)(W1 + kbase * 128 + c * 4);
        }
        // stage x tile transposed: 32 rows x 64 k; thread t -> row t>>3, k-chunk (t&7)*8
        {
            int r = t >> 3, kc = (t & 7) * 8;
            int grow = row0 + r; if (grow >= N_NODES) grow = N_NODES - 1;
            const float* p = x + grow * 128 + kbase + kc;
            float4 a = *(const float4*)p;
            float4 b = *(const float4*)(p + 4);
            xT[(kc + 0) * 32 + r] = a.x; xT[(kc + 1) * 32 + r] = a.y;
            xT[(kc + 2) * 32 + r] = a.z; xT[(kc + 3) * 32 + r] = a.w;
            xT[(kc + 4) * 32 + r] = b.x; xT[(kc + 5) * 32 + r] = b.y;
            xT[(kc + 6) * 32 + r] = b.z; xT[(kc + 7) * 32 + r] = b.w;
        }
        __syncthreads();
        #pragma unroll 8
        for (int k = 0; k < 64; k++) {
            float4 a  = *(const float4*)&xT[k * 32 + ty * 4];
            float4 wv = *(const float4*)&Wf[k * 128 + tx * 4];
            acc[0][0]=fmaf(a.x,wv.x,acc[0][0]); acc[0][1]=fmaf(a.x,wv.y,acc[0][1]); acc[0][2]=fmaf(a.x,wv.z,acc[0][2]); acc[0][3]=fmaf(a.x,wv.w,acc[0][3]);
            acc[1][0]=fmaf(a.y,wv.x,acc[1][0]); acc[1][1]=fmaf(a.y,wv.y,acc[1][1]); acc[1][2]=fmaf(a.y,wv.z,acc[1][2]); acc[1][3]=fmaf(a.y,wv.w,acc[1][3]);
            acc[2][0]=fmaf(a.z,wv.x,acc[2][0]); acc[2][1]=fmaf(a.z,wv.y,acc[2][1]); acc[2][2]=fmaf(a.z,wv.z,acc[2][2]); acc[2][3]=fmaf(a.z,wv.w,acc[2][3]);
            acc[3][0]=fmaf(a.w,wv.x,acc[3][0]); acc[3][1]=fmaf(a.w,wv.y,acc[3][1]); acc[3][2]=fmaf(a.w,wv.z,acc[3][2]); acc[3][3]=fmaf(a.w,wv.w,acc[3][3]);
        }
        __syncthreads();
    }
    #pragma unroll
    for (int i = 0; i < 4; i++) {
        int row = row0 + ty * 4 + i;
        if (row < N_NODES) {
            *(float4*)(h1 + row * 128 + tx * 4) =
                make_float4(acc[i][0], acc[i][1], acc[i][2], acc[i][3]);
        }
    }
}

// ---------- 6. agg1: sum coef*h1[src] + dinv^2*h1[v] + b1, ReLU -> r1 ----------
__global__ __launch_bounds__(256) void k_agg1(const float* __restrict__ h1,
                                              const int* __restrict__ csr_s,
                                              const float* __restrict__ csr_c,
                                              const int* __restrict__ offs,
                                              const int* __restrict__ counts,
                                              const float* __restrict__ dinv,
                                              const float* __restrict__ b1,
                                              float* __restrict__ r1) {
    int v = (blockIdx.x * 256 + threadIdx.x) >> 6;  // wave per node
    int lane = threadIdx.x & 63;
    if (v >= N_NODES) return;
    int start = offs[v], n = counts[v];
    float a0 = 0.f, a1 = 0.f;
    for (int i = 0; i < n; i++) {
        int s = csr_s[start + i];
        float cf = csr_c[start + i];
        float2 p = *(const float2*)(h1 + s * 128 + lane * 2);
        a0 = fmaf(cf, p.x, a0);
        a1 = fmaf(cf, p.y, a1);
    }
    float di = dinv[v], d2 = di * di;
    float2 pv = *(const float2*)(h1 + v * 128 + lane * 2);
    a0 = fmaf(d2, pv.x, a0);
    a1 = fmaf(d2, pv.y, a1);
    float2 pb = *(const float2*)(b1 + lane * 2);
    a0 = fmaxf(a0 + pb.x, 0.f);
    a1 = fmaxf(a1 + pb.y, 0.f);
    *(float2*)(r1 + v * 128 + lane * 2) = make_float2(a0, a1);
}

// ---------- 7. GEMM2: h2[50000,64] = r1[50000,128] @ W2[128,64] ----------
__global__ __launch_bounds__(256) void k_gemm2(const float* __restrict__ r1,
                                               const float* __restrict__ W2,
                                               float* __restrict__ h2) {
    __shared__ float Wf[64 * 64];   // 16 KB: K-half of W2 [k][n]
    __shared__ float xT[64 * 64];   // 16 KB: xT[k][r], 64-row tile
    int t = threadIdx.x;
    int row0 = blockIdx.x * 64;
    int tx = t & 15, ty = t >> 4;   // cols 4*tx (0..63), rows 4*ty (0..63)
    float acc[4][4] = {};
    for (int kh = 0; kh < 2; kh++) {
        int kbase = kh * 64;
        // stage W2 half: 64*64 floats = 1024 float4s
        for (int c = t; c < 1024; c += 256) {
            *(float4*)&Wf[c * 4] = *(const float4*)(W2 + kbase * 64 + c * 4);
        }
        // stage r1 tile transposed: 64 rows x 64 k; chunk c -> row c>>3, k-chunk (c&7)*8
        for (int c = t; c < 512; c += 256) {
            int r = c >> 3, kc = (c & 7) * 8;
            int grow = row0 + r; if (grow >= N_NODES) grow = N_NODES - 1;
            const float* p = r1 + grow * 128 + kbase + kc;
            float4 a = *(const float4*)p;
            float4 b = *(const float4*)(p + 4);
            xT[(kc + 0) * 64 + r] = a.x; xT[(kc + 1) * 64 + r] = a.y;
            xT[(kc + 2) * 64 + r] = a.z; xT[(kc + 3) * 64 + r] = a.w;
            xT[(kc + 4) * 64 + r] = b.x; xT[(kc + 5) * 64 + r] = b.y;
            xT[(kc + 6) * 64 + r] = b.z; xT[(kc + 7) * 64 + r] = b.w;
        }
        __syncthreads();
        #pragma unroll 8
        for (int k = 0; k < 64; k++) {
            float4 a  = *(const float4*)&xT[k * 64 + ty * 4];
            float4 wv = *(const float4*)&Wf[k * 64 + tx * 4];
            acc[0][0]=fmaf(a.x,wv.x,acc[0][0]); acc[0][1]=fmaf(a.x,wv.y,acc[0][1]); acc[0][2]=fmaf(a.x,wv.z,acc[0][2]); acc[0][3]=fmaf(a.x,wv.w,acc[0][3]);
            acc[1][0]=fmaf(a.y,wv.x,acc[1][0]); acc[1][1]=fmaf(a.y,wv.y,acc[1][1]); acc[1][2]=fmaf(a.y,wv.z,acc[1][2]); acc[1][3]=fmaf(a.y,wv.w,acc[1][3]);
            acc[2][0]=fmaf(a.z,wv.x,acc[2][0]); acc[2][1]=fmaf(a.z,wv.y,acc[2][1]); acc[2][2]=fmaf(a.z,wv.z,acc[2][2]); acc[2][3]=fmaf(a.z,wv.w,acc[2][3]);
            acc[3][0]=fmaf(a.w,wv.x,acc[3][0]); acc[3][1]=fmaf(a.w,wv.y,acc[3][1]); acc[3][2]=fmaf(a.w,wv.z,acc[3][2]); acc[3][3]=fmaf(a.w,wv.w,acc[3][3]);
        }
        __syncthreads();
    }
    #pragma unroll
    for (int i = 0; i < 4; i++) {
        int row = row0 + ty * 4 + i;
        if (row < N_NODES) {
            *(float4*)(h2 + row * 64 + tx * 4) =
                make_float4(acc[i][0], acc[i][1], acc[i][2], acc[i][3]);
        }
    }
}

// ---------- 8. agg2 + head: aggregate h2, +b2, ReLU, @Wo+bo, log_softmax ----------
__global__ __launch_bounds__(256) void k_agg2(const float* __restrict__ h2,
                                              const int* __restrict__ csr_s,
                                              const float* __restrict__ csr_c,
                                              const int* __restrict__ offs,
                                              const int* __restrict__ counts,
                                              const float* __restrict__ dinv,
                                              const float* __restrict__ b2,
                                              const float* __restrict__ Wo,
                                              const float* __restrict__ bo,
                                              float* __restrict__ out) {
    int v = (blockIdx.x * 256 + threadIdx.x) >> 6;  // wave per node
    int lane = threadIdx.x & 63;
    if (v >= N_NODES) return;
    int start = offs[v], n = counts[v];
    float a = 0.f;
    for (int i = 0; i < n; i++) {
        int s = csr_s[start + i];
        float cf = csr_c[start + i];
        a = fmaf(cf, h2[s * 64 + lane], a);
    }
    float di = dinv[v];
    a = fmaf(di * di, h2[v * 64 + lane], a);
    a += b2[lane];
    a = fmaxf(a, 0.f);  // h3[lane]
    float2 pw = *(const float2*)(Wo + lane * 2);  // Wo[lane][0], Wo[lane][1]
    float l0 = a * pw.x;
    float l1 = a * pw.y;
    #pragma unroll
    for (int off = 32; off > 0; off >>= 1) {
        l0 += __shfl_down(l0, off);
        l1 += __shfl_down(l1, off);
    }
    if (lane == 0) {
        l0 += bo[0]; l1 += bo[1];
        float m = fmaxf(l0, l1);
        float ls = m + __logf(__expf(l0 - m) + __expf(l1 - m));
        *(float2*)(out + v * 2) = make_float2(l0 - ls, l1 - ls);
    }
}

extern "C" void kernel_launch(void* const* d_in, const int* in_sizes, int n_in,
                              void* d_out, int out_size, void* d_ws, size_t ws_size,
                              hipStream_t stream) {
    const float* x  = (const float*)d_in[0];
    const int* ei   = (const int*)d_in[1];
    const float* W1 = (const float*)d_in[2];
    const float* b1 = (const float*)d_in[3];
    const float* W2 = (const float*)d_in[4];
    const float* b2 = (const float*)d_in[5];
    const float* Wo = (const float*)d_in[6];
    const float* bo = (const float*)d_in[7];
    float* out      = (float*)d_out;
    const int* src = ei;             // edge_index[0]
    const int* dst = ei + N_EDGES;   // edge_index[1]

    char* w = (char*)d_ws;
    int*   counts = (int*)(w + 0);          // 200 KB
    int*   offs   = (int*)(w + 200704);     // 200 KB
    int*   cursor = (int*)(w + 401408);     // 200 KB
    int*   bsums  = (int*)(w + 602112);     // 1 KB
    float* dinv   = (float*)(w + 603136);   // 200 KB
    int*   csr_s  = (int*)(w + 803840);     // 3.2 MB
    float* csr_c  = (float*)(w + 4003840);  // 3.2 MB
    float* h1     = (float*)(w + 7203840);  // 25.6 MB  (reused as h2 later)
    float* r1     = (float*)(w + 32803840); // 25.6 MB
    float* h2     = h1;                     // h1 dead after agg1
    // total ws usage: ~58.4 MB

    hipMemsetAsync(counts, 0, N_NODES * sizeof(int), stream);
    hipMemsetAsync(cursor, 0, N_NODES * sizeof(int), stream);

    int nb = (N_NODES + 255) / 256;
    k_count  <<<(N_EDGES + 255) / 256, 256, 0, stream>>>(dst, counts);
    k_dinv   <<<nb, 256, 0, stream>>>(counts, dinv);
    k_scan1  <<<nb, 256, 0, stream>>>(counts, offs, bsums);
    k_scan2  <<<1, 256, 0, stream>>>(bsums, nb);
    k_scan3  <<<nb, 256, 0, stream>>>(offs, bsums);
    k_scatter<<<(N_EDGES + 255) / 256, 256, 0, stream>>>(src, dst, offs, cursor, dinv, csr_s, csr_c);

    k_gemm1  <<<(N_NODES + 31) / 32, 256, 0, stream>>>(x, W1, h1);
    k_agg1   <<<(N_NODES + 3) / 4, 256, 0, stream>>>(h1, csr_s, csr_c, offs, counts, dinv, b1, r1);
    k_gemm2  <<<(N_NODES + 63) / 64, 256, 0, stream>>>(r1, W2, h2);
    k_agg2   <<<(N_NODES + 3) / 4, 256, 0, stream>>>(h2, csr_s, csr_c, offs, counts, dinv, b2, Wo, bo, out);
}

// Round 3
// 323.014 us; speedup vs baseline: 1.2169x; 1.2169x over previous
//
#include <hip/hip_runtime.h>
#include <stdint.h>

#define N_NODES 50000
#define N_EDGES 800000
// D_IN=128, H1=128, H2=64, C=2 — inputs fp32; intermediates bf16

// ---------- bf16 helpers ----------
__device__ __forceinline__ float bflo(uint32_t u) { return __uint_as_float(u << 16); }
__device__ __forceinline__ float bfhi(uint32_t u) { return __uint_as_float(u & 0xffff0000u); }
__device__ __forceinline__ float b2f(unsigned short s) { return __uint_as_float(((uint32_t)s) << 16); }
__device__ __forceinline__ unsigned short f2b(float f) {
    uint32_t u = __float_as_uint(f);
    u += 0x7fffu + ((u >> 16) & 1u);   // RNE
    return (unsigned short)(u >> 16);
}

// ---------- 1. in-degree count ----------
__global__ void k_count(const int* __restrict__ dst, int* __restrict__ counts) {
    int e = blockIdx.x * 256 + threadIdx.x;
    if (e < N_EDGES) {
        int d = dst[e];
        if ((unsigned)d < N_NODES) atomicAdd(&counts[d], 1);
    }
}

// ---------- 2. dinv = rsqrt(deg+1) ----------
__global__ void k_dinv(const int* __restrict__ counts, float* __restrict__ dinv) {
    int i = blockIdx.x * 256 + threadIdx.x;
    if (i < N_NODES) dinv[i] = rsqrtf((float)counts[i] + 1.0f);
}

// ---------- 3a. per-block exclusive scan of counts ----------
__global__ void k_scan1(const int* __restrict__ counts, int* __restrict__ offs,
                        int* __restrict__ bsums) {
    int t = threadIdx.x, b = blockIdx.x;
    int idx = b * 256 + t;
    int c = (idx < N_NODES) ? counts[idx] : 0;
    int v = c;
    int lane = t & 63, w = t >> 6;
    #pragma unroll
    for (int off = 1; off < 64; off <<= 1) {
        int u = __shfl_up(v, off);
        if (lane >= off) v += u;
    }
    __shared__ int wt[4];
    if (lane == 63) wt[w] = v;
    __syncthreads();
    int base = 0;
    for (int j = 0; j < w; j++) base += wt[j];
    if (idx < N_NODES) offs[idx] = base + v - c;
    if (t == 255) bsums[b] = base + v;
}

// ---------- 3b. exclusive scan of block sums (nb <= 256) ----------
__global__ void k_scan2(int* __restrict__ bsums, int nb) {
    int t = threadIdx.x;
    int c = (t < nb) ? bsums[t] : 0;
    int v = c;
    int lane = t & 63, w = t >> 6;
    #pragma unroll
    for (int off = 1; off < 64; off <<= 1) {
        int u = __shfl_up(v, off);
        if (lane >= off) v += u;
    }
    __shared__ int wt[4];
    if (lane == 63) wt[w] = v;
    __syncthreads();
    int base = 0;
    for (int j = 0; j < w; j++) base += wt[j];
    if (t < nb) bsums[t] = base + v - c;
}

// ---------- 3c. add block bases ----------
__global__ void k_scan3(int* __restrict__ offs, const int* __restrict__ bsums) {
    int idx = blockIdx.x * 256 + threadIdx.x;
    if (idx < N_NODES) offs[idx] += bsums[idx >> 8];
}

// ---------- 4. scatter edges into CSR records {src, coef} grouped by dst ----------
__global__ void k_scatter(const int* __restrict__ src, const int* __restrict__ dst,
                          const int* __restrict__ offs, int* __restrict__ cursor,
                          const float* __restrict__ dinv,
                          int2* __restrict__ csr) {
    int e = blockIdx.x * 256 + threadIdx.x;
    if (e >= N_EDGES) return;
    int s = src[e], d = dst[e];
    if ((unsigned)s >= N_NODES || (unsigned)d >= N_NODES) return;
    int pos = offs[d] + atomicAdd(&cursor[d], 1);
    csr[pos] = make_int2(s, __float_as_int(dinv[s] * dinv[d]));
}

// ---------- 5. GEMM1: h1b[50000,128](bf16) = x[50000,128] @ W1[128,128] ----------
__global__ __launch_bounds__(256) void k_gemm1(const float* __restrict__ x,
                                               const float* __restrict__ W1,
                                               unsigned short* __restrict__ h1b) {
    __shared__ float Wf[64 * 128];  // 32 KB: K-half of W1 [k][n]
    __shared__ float xT[64 * 32];   // 8 KB: xT[k][r]
    int t = threadIdx.x;
    int row0 = blockIdx.x * 32;
    int tx = t & 31, ty = t >> 5;
    float acc[4][4] = {};
    for (int kh = 0; kh < 2; kh++) {
        int kbase = kh * 64;
        for (int c = t; c < 2048; c += 256) {
            *(float4*)&Wf[c * 4] = *(const float4*)(W1 + kbase * 128 + c * 4);
        }
        {
            int r = t >> 3, kc = (t & 7) * 8;
            int grow = row0 + r; if (grow >= N_NODES) grow = N_NODES - 1;
            const float* p = x + grow * 128 + kbase + kc;
            float4 a = *(const float4*)p;
            float4 b = *(const float4*)(p + 4);
            xT[(kc + 0) * 32 + r] = a.x; xT[(kc + 1) * 32 + r] = a.y;
            xT[(kc + 2) * 32 + r] = a.z; xT[(kc + 3) * 32 + r] = a.w;
            xT[(kc + 4) * 32 + r] = b.x; xT[(kc + 5) * 32 + r] = b.y;
            xT[(kc + 6) * 32 + r] = b.z; xT[(kc + 7) * 32 + r] = b.w;
        }
        __syncthreads();
        #pragma unroll 8
        for (int k = 0; k < 64; k++) {
            float4 a  = *(const float4*)&xT[k * 32 + ty * 4];
            float4 wv = *(const float4*)&Wf[k * 128 + tx * 4];
            acc[0][0]=fmaf(a.x,wv.x,acc[0][0]); acc[0][1]=fmaf(a.x,wv.y,acc[0][1]); acc[0][2]=fmaf(a.x,wv.z,acc[0][2]); acc[0][3]=fmaf(a.x,wv.w,acc[0][3]);
            acc[1][0]=fmaf(a.y,wv.x,acc[1][0]); acc[1][1]=fmaf(a.y,wv.y,acc[1][1]); acc[1][2]=fmaf(a.y,wv.z,acc[1][2]); acc[1][3]=fmaf(a.y,wv.w,acc[1][3]);
            acc[2][0]=fmaf(a.z,wv.x,acc[2][0]); acc[2][1]=fmaf(a.z,wv.y,acc[2][1]); acc[2][2]=fmaf(a.z,wv.z,acc[2][2]); acc[2][3]=fmaf(a.z,wv.w,acc[2][3]);
            acc[3][0]=fmaf(a.w,wv.x,acc[3][0]); acc[3][1]=fmaf(a.w,wv.y,acc[3][1]); acc[3][2]=fmaf(a.w,wv.z,acc[3][2]); acc[3][3]=fmaf(a.w,wv.w,acc[3][3]);
        }
        __syncthreads();
    }
    #pragma unroll
    for (int i = 0; i < 4; i++) {
        int row = row0 + ty * 4 + i;
        if (row < N_NODES) {
            uint2 o;
            o.x = (uint32_t)f2b(acc[i][0]) | ((uint32_t)f2b(acc[i][1]) << 16);
            o.y = (uint32_t)f2b(acc[i][2]) | ((uint32_t)f2b(acc[i][3]) << 16);
            *(uint2*)(h1b + row * 128 + tx * 4) = o;
        }
    }
}

// ---------- 6. agg1: r1b = relu(sum coef*h1b[src] + dinv^2*h1b[v] + b1) ----------
__global__ __launch_bounds__(256) void k_agg1(const unsigned short* __restrict__ h1b,
                                              const int2* __restrict__ csr,
                                              const int* __restrict__ offs,
                                              const int* __restrict__ counts,
                                              const float* __restrict__ dinv,
                                              const float* __restrict__ b1,
                                              unsigned short* __restrict__ r1b) {
    int v = (blockIdx.x * 256 + threadIdx.x) >> 6;  // wave per node
    int lane = threadIdx.x & 63;
    if (v >= N_NODES) return;
    int start = offs[v], n = counts[v];
    const int2* cp = csr + start;
    float a0 = 0.f, a1 = 0.f;
    for (int base = 0; base < n; base += 64) {
        int m = n - base; if (m > 64) m = 64;
        int2 e = make_int2(0, 0);
        if (lane < m) e = cp[base + lane];          // coalesced edge-record load
        #pragma unroll 4
        for (int i = 0; i < m; i++) {
            int s    = __shfl(e.x, i);
            float cf = __uint_as_float((uint32_t)__shfl(e.y, i));
            uint32_t p = *(const uint32_t*)(h1b + s * 128 + lane * 2);  // 2 bf16 cols
            a0 = fmaf(cf, bflo(p), a0);
            a1 = fmaf(cf, bfhi(p), a1);
        }
    }
    float di = dinv[v], d2 = di * di;
    uint32_t pv = *(const uint32_t*)(h1b + v * 128 + lane * 2);
    a0 = fmaf(d2, bflo(pv), a0);
    a1 = fmaf(d2, bfhi(pv), a1);
    float2 pb = *(const float2*)(b1 + lane * 2);
    a0 = fmaxf(a0 + pb.x, 0.f);
    a1 = fmaxf(a1 + pb.y, 0.f);
    *(uint32_t*)(r1b + v * 128 + lane * 2) = (uint32_t)f2b(a0) | ((uint32_t)f2b(a1) << 16);
}

// ---------- 7. GEMM2: h2b[50000,64](bf16) = r1b[50000,128] @ W2[128,64] ----------
__global__ __launch_bounds__(256) void k_gemm2(const unsigned short* __restrict__ r1b,
                                               const float* __restrict__ W2,
                                               unsigned short* __restrict__ h2b) {
    __shared__ float Wf[64 * 64];   // 16 KB
    __shared__ float xT[64 * 64];   // 16 KB
    int t = threadIdx.x;
    int row0 = blockIdx.x * 64;
    int tx = t & 15, ty = t >> 4;
    float acc[4][4] = {};
    for (int kh = 0; kh < 2; kh++) {
        int kbase = kh * 64;
        for (int c = t; c < 1024; c += 256) {
            *(float4*)&Wf[c * 4] = *(const float4*)(W2 + kbase * 64 + c * 4);
        }
        for (int c = t; c < 512; c += 256) {
            int r = c >> 3, kc = (c & 7) * 8;
            int grow = row0 + r; if (grow >= N_NODES) grow = N_NODES - 1;
            uint4 p = *(const uint4*)(r1b + grow * 128 + kbase + kc);  // 8 bf16
            xT[(kc + 0) * 64 + r] = bflo(p.x); xT[(kc + 1) * 64 + r] = bfhi(p.x);
            xT[(kc + 2) * 64 + r] = bflo(p.y); xT[(kc + 3) * 64 + r] = bfhi(p.y);
            xT[(kc + 4) * 64 + r] = bflo(p.z); xT[(kc + 5) * 64 + r] = bfhi(p.z);
            xT[(kc + 6) * 64 + r] = bflo(p.w); xT[(kc + 7) * 64 + r] = bfhi(p.w);
        }
        __syncthreads();
        #pragma unroll 8
        for (int k = 0; k < 64; k++) {
            float4 a  = *(const float4*)&xT[k * 64 + ty * 4];
            float4 wv = *(const float4*)&Wf[k * 64 + tx * 4];
            acc[0][0]=fmaf(a.x,wv.x,acc[0][0]); acc[0][1]=fmaf(a.x,wv.y,acc[0][1]); acc[0][2]=fmaf(a.x,wv.z,acc[0][2]); acc[0][3]=fmaf(a.x,wv.w,acc[0][3]);
            acc[1][0]=fmaf(a.y,wv.x,acc[1][0]); acc[1][1]=fmaf(a.y,wv.y,acc[1][1]); acc[1][2]=fmaf(a.y,wv.z,acc[1][2]); acc[1][3]=fmaf(a.y,wv.w,acc[1][3]);
            acc[2][0]=fmaf(a.z,wv.x,acc[2][0]); acc[2][1]=fmaf(a.z,wv.y,acc[2][1]); acc[2][2]=fmaf(a.z,wv.z,acc[2][2]); acc[2][3]=fmaf(a.z,wv.w,acc[2][3]);
            acc[3][0]=fmaf(a.w,wv.x,acc[3][0]); acc[3][1]=fmaf(a.w,wv.y,acc[3][1]); acc[3][2]=fmaf(a.w,wv.z,acc[3][2]); acc[3][3]=fmaf(a.w,wv.w,acc[3][3]);
        }
        __syncthreads();
    }
    #pragma unroll
    for (int i = 0; i < 4; i++) {
        int row = row0 + ty * 4 + i;
        if (row < N_NODES) {
            uint2 o;
            o.x = (uint32_t)f2b(acc[i][0]) | ((uint32_t)f2b(acc[i][1]) << 16);
            o.y = (uint32_t)f2b(acc[i][2]) | ((uint32_t)f2b(acc[i][3]) << 16);
            *(uint2*)(h2b + row * 64 + tx * 4) = o;
        }
    }
}

// ---------- 8. agg2 + head: aggregate h2b, +b2, ReLU, @Wo+bo, log_softmax ----------
__global__ __launch_bounds__(256) void k_agg2(const unsigned short* __restrict__ h2b,
                                              const int2* __restrict__ csr,
                                              const int* __restrict__ offs,
                                              const int* __restrict__ counts,
                                              const float* __restrict__ dinv,
                                              const float* __restrict__ b2,
                                              const float* __restrict__ Wo,
                                              const float* __restrict__ bo,
                                              float* __restrict__ out) {
    int v = (blockIdx.x * 256 + threadIdx.x) >> 6;  // wave per node
    int lane = threadIdx.x & 63;
    if (v >= N_NODES) return;
    int start = offs[v], n = counts[v];
    const int2* cp = csr + start;
    float a = 0.f;
    for (int base = 0; base < n; base += 64) {
        int m = n - base; if (m > 64) m = 64;
        int2 e = make_int2(0, 0);
        if (lane < m) e = cp[base + lane];
        #pragma unroll 4
        for (int i = 0; i < m; i++) {
            int s    = __shfl(e.x, i);
            float cf = __uint_as_float((uint32_t)__shfl(e.y, i));
            a = fmaf(cf, b2f(h2b[s * 64 + lane]), a);
        }
    }
    float di = dinv[v];
    a = fmaf(di * di, b2f(h2b[v * 64 + lane]), a);
    a += b2[lane];
    a = fmaxf(a, 0.f);  // h3[lane]
    float2 pw = *(const float2*)(Wo + lane * 2);
    float l0 = a * pw.x;
    float l1 = a * pw.y;
    #pragma unroll
    for (int off = 32; off > 0; off >>= 1) {
        l0 += __shfl_down(l0, off);
        l1 += __shfl_down(l1, off);
    }
    if (lane == 0) {
        l0 += bo[0]; l1 += bo[1];
        float m = fmaxf(l0, l1);
        float ls = m + __logf(__expf(l0 - m) + __expf(l1 - m));
        *(float2*)(out + v * 2) = make_float2(l0 - ls, l1 - ls);
    }
}

extern "C" void kernel_launch(void* const* d_in, const int* in_sizes, int n_in,
                              void* d_out, int out_size, void* d_ws, size_t ws_size,
                              hipStream_t stream) {
    const float* x  = (const float*)d_in[0];
    const int* ei   = (const int*)d_in[1];
    const float* W1 = (const float*)d_in[2];
    const float* b1 = (const float*)d_in[3];
    const float* W2 = (const float*)d_in[4];
    const float* b2 = (const float*)d_in[5];
    const float* Wo = (const float*)d_in[6];
    const float* bo = (const float*)d_in[7];
    float* out      = (float*)d_out;
    const int* src = ei;             // edge_index[0]
    const int* dst = ei + N_EDGES;   // edge_index[1]

    char* w = (char*)d_ws;
    int*   counts = (int*)(w + 0);          // 200 KB
    int*   offs   = (int*)(w + 200704);     // 200 KB
    int*   cursor = (int*)(w + 401408);     // 200 KB
    int*   bsums  = (int*)(w + 602112);     // 1 KB
    float* dinv   = (float*)(w + 603136);   // 200 KB
    int2*  csr    = (int2*)(w + 803840);    // 6.4 MB {src, coef}
    unsigned short* h1b = (unsigned short*)(w + 7203840);   // 12.8 MB
    unsigned short* r1b = (unsigned short*)(w + 20003840);  // 12.8 MB
    unsigned short* h2b = (unsigned short*)(w + 32803840);  // 6.4 MB
    // total ws usage: ~39.2 MB

    hipMemsetAsync(counts, 0, N_NODES * sizeof(int), stream);
    hipMemsetAsync(cursor, 0, N_NODES * sizeof(int), stream);

    int nb = (N_NODES + 255) / 256;
    k_count  <<<(N_EDGES + 255) / 256, 256, 0, stream>>>(dst, counts);
    k_dinv   <<<nb, 256, 0, stream>>>(counts, dinv);
    k_scan1  <<<nb, 256, 0, stream>>>(counts, offs, bsums);
    k_scan2  <<<1, 256, 0, stream>>>(bsums, nb);
    k_scan3  <<<nb, 256, 0, stream>>>(offs, bsums);
    k_scatter<<<(N_EDGES + 255) / 256, 256, 0, stream>>>(src, dst, offs, cursor, dinv, csr);

    k_gemm1  <<<(N_NODES + 31) / 32, 256, 0, stream>>>(x, W1, h1b);
    k_agg1   <<<(N_NODES + 3) / 4, 256, 0, stream>>>(h1b, csr, offs, counts, dinv, b1, r1b);
    k_gemm2  <<<(N_NODES + 63) / 64, 256, 0, stream>>>(r1b, W2, h2b);
    k_agg2   <<<(N_NODES + 3) / 4, 256, 0, stream>>>(h2b, csr, offs, counts, dinv, b2, Wo, bo, out);
}

// Round 4
// 290.729 us; speedup vs baseline: 1.3520x; 1.1111x over previous
//
#include <hip/hip_runtime.h>
#include <stdint.h>

#define N_NODES 50000
#define N_EDGES 800000
// D_IN=128, H1=128, H2=64, C=2 — inputs fp32; intermediates bf16 (dinv-prescaled rows)

// ---------- bf16 helpers ----------
__device__ __forceinline__ float bflo(uint32_t u) { return __uint_as_float(u << 16); }
__device__ __forceinline__ float bfhi(uint32_t u) { return __uint_as_float(u & 0xffff0000u); }
__device__ __forceinline__ unsigned short f2b(float f) {
    uint32_t u = __float_as_uint(f);
    u += 0x7fffu + ((u >> 16) & 1u);   // RNE
    return (unsigned short)(u >> 16);
}

// ---------- 1. in-degree count ----------
__global__ void k_count(const int* __restrict__ dst, int* __restrict__ counts) {
    int e = blockIdx.x * 256 + threadIdx.x;
    if (e < N_EDGES) {
        int d = dst[e];
        if ((unsigned)d < N_NODES) atomicAdd(&counts[d], 1);
    }
}

// ---------- 2a. per-block exclusive scan of counts (+ dinv fused) ----------
__global__ void k_scan1(const int* __restrict__ counts, int* __restrict__ offs,
                        int* __restrict__ bsums, float* __restrict__ dinv) {
    int t = threadIdx.x, b = blockIdx.x;
    int idx = b * 256 + t;
    int c = (idx < N_NODES) ? counts[idx] : 0;
    if (idx < N_NODES) dinv[idx] = rsqrtf((float)c + 1.0f);
    int v = c;
    int lane = t & 63, w = t >> 6;
    #pragma unroll
    for (int off = 1; off < 64; off <<= 1) {
        int u = __shfl_up(v, off);
        if (lane >= off) v += u;
    }
    __shared__ int wt[4];
    if (lane == 63) wt[w] = v;
    __syncthreads();
    int base = 0;
    for (int j = 0; j < w; j++) base += wt[j];
    if (idx < N_NODES) offs[idx] = base + v - c;
    if (t == 255) bsums[b] = base + v;
}

// ---------- 2b. exclusive scan of block sums (nb <= 256) ----------
__global__ void k_scan2(int* __restrict__ bsums, int nb) {
    int t = threadIdx.x;
    int c = (t < nb) ? bsums[t] : 0;
    int v = c;
    int lane = t & 63, w = t >> 6;
    #pragma unroll
    for (int off = 1; off < 64; off <<= 1) {
        int u = __shfl_up(v, off);
        if (lane >= off) v += u;
    }
    __shared__ int wt[4];
    if (lane == 63) wt[w] = v;
    __syncthreads();
    int base = 0;
    for (int j = 0; j < w; j++) base += wt[j];
    if (t < nb) bsums[t] = base + v - c;
}

// ---------- 2c. add block bases ----------
__global__ void k_scan3(int* __restrict__ offs, const int* __restrict__ bsums) {
    int idx = blockIdx.x * 256 + threadIdx.x;
    if (idx < N_NODES) offs[idx] += bsums[idx >> 8];
}

// ---------- 3. scatter: csr_s (src only), grouped by dst ----------
__global__ void k_scatter(const int* __restrict__ src, const int* __restrict__ dst,
                          const int* __restrict__ offs, int* __restrict__ cursor,
                          int* __restrict__ csr_s) {
    int e = blockIdx.x * 256 + threadIdx.x;
    if (e >= N_EDGES) return;
    int s = src[e], d = dst[e];
    if ((unsigned)s >= N_NODES || (unsigned)d >= N_NODES) return;
    int pos = offs[d] + atomicAdd(&cursor[d], 1);
    csr_s[pos] = s;
}

// ---------- 4. GEMM1: h1s[v] = dinv[v] * (x[v] @ W1)  (bf16 out) ----------
__global__ __launch_bounds__(256) void k_gemm1(const float* __restrict__ x,
                                               const float* __restrict__ W1,
                                               const float* __restrict__ dinv,
                                               unsigned short* __restrict__ h1s) {
    __shared__ float Wf[64 * 128];  // 32 KB
    __shared__ float xT[64 * 32];   // 8 KB
    int t = threadIdx.x;
    int row0 = blockIdx.x * 32;
    int tx = t & 31, ty = t >> 5;
    float acc[4][4] = {};
    for (int kh = 0; kh < 2; kh++) {
        int kbase = kh * 64;
        for (int c = t; c < 2048; c += 256) {
            *(float4*)&Wf[c * 4] = *(const float4*)(W1 + kbase * 128 + c * 4);
        }
        {
            int r = t >> 3, kc = (t & 7) * 8;
            int grow = row0 + r; if (grow >= N_NODES) grow = N_NODES - 1;
            const float* p = x + grow * 128 + kbase + kc;
            float4 a = *(const float4*)p;
            float4 b = *(const float4*)(p + 4);
            xT[(kc + 0) * 32 + r] = a.x; xT[(kc + 1) * 32 + r] = a.y;
            xT[(kc + 2) * 32 + r] = a.z; xT[(kc + 3) * 32 + r] = a.w;
            xT[(kc + 4) * 32 + r] = b.x; xT[(kc + 5) * 32 + r] = b.y;
            xT[(kc + 6) * 32 + r] = b.z; xT[(kc + 7) * 32 + r] = b.w;
        }
        __syncthreads();
        #pragma unroll 8
        for (int k = 0; k < 64; k++) {
            float4 a  = *(const float4*)&xT[k * 32 + ty * 4];
            float4 wv = *(const float4*)&Wf[k * 128 + tx * 4];
            acc[0][0]=fmaf(a.x,wv.x,acc[0][0]); acc[0][1]=fmaf(a.x,wv.y,acc[0][1]); acc[0][2]=fmaf(a.x,wv.z,acc[0][2]); acc[0][3]=fmaf(a.x,wv.w,acc[0][3]);
            acc[1][0]=fmaf(a.y,wv.x,acc[1][0]); acc[1][1]=fmaf(a.y,wv.y,acc[1][1]); acc[1][2]=fmaf(a.y,wv.z,acc[1][2]); acc[1][3]=fmaf(a.y,wv.w,acc[1][3]);
            acc[2][0]=fmaf(a.z,wv.x,acc[2][0]); acc[2][1]=fmaf(a.z,wv.y,acc[2][1]); acc[2][2]=fmaf(a.z,wv.z,acc[2][2]); acc[2][3]=fmaf(a.z,wv.w,acc[2][3]);
            acc[3][0]=fmaf(a.w,wv.x,acc[3][0]); acc[3][1]=fmaf(a.w,wv.y,acc[3][1]); acc[3][2]=fmaf(a.w,wv.z,acc[3][2]); acc[3][3]=fmaf(a.w,wv.w,acc[3][3]);
        }
        __syncthreads();
    }
    #pragma unroll
    for (int i = 0; i < 4; i++) {
        int row = row0 + ty * 4 + i;
        if (row < N_NODES) {
            float di = dinv[row];
            uint2 o;
            o.x = (uint32_t)f2b(di * acc[i][0]) | ((uint32_t)f2b(di * acc[i][1]) << 16);
            o.y = (uint32_t)f2b(di * acc[i][2]) | ((uint32_t)f2b(di * acc[i][3]) << 16);
            *(uint2*)(h1s + row * 128 + tx * 4) = o;
        }
    }
}

// ---------- 5. agg1: r1b[v] = relu(dinv[v]*Σ_{s∈N(v)∪{v}} h1s[s] + b1) ----------
// 2 nodes per wave: lanes 0-31 -> v0 = 2w, lanes 32-63 -> v1 = 2w+1.
// Each lane covers 4 bf16 cols (8 B) of its node's 256 B row.
__global__ __launch_bounds__(256) void k_agg1(const unsigned short* __restrict__ h1s,
                                              const int* __restrict__ csr_s,
                                              const int* __restrict__ offs,
                                              const int* __restrict__ counts,
                                              const float* __restrict__ dinv,
                                              const float* __restrict__ b1,
                                              unsigned short* __restrict__ r1b) {
    int wave = (blockIdx.x * 256 + threadIdx.x) >> 6;
    int lane = threadIdx.x & 63;
    int half = lane >> 5, l = lane & 31;
    int v = wave * 2 + half;
    if (v >= N_NODES) return;
    int start = offs[v], n = counts[v];
    const int* cs = csr_s + start;
    int nmax = max(n, __shfl(n, lane ^ 32));
    float a0 = 0.f, a1 = 0.f, a2 = 0.f, a3 = 0.f;
    // self-loop row
    {
        uint2 p = *(const uint2*)(h1s + v * 128 + l * 4);
        a0 = bflo(p.x); a1 = bfhi(p.x); a2 = bflo(p.y); a3 = bfhi(p.y);
    }
    for (int base = 0; base < nmax; base += 32) {
        int idx = base + l;
        int e = (idx < n) ? cs[idx] : 0;   // coalesced per half
        int mm = nmax - base; if (mm > 32) mm = 32;
        #pragma unroll 4
        for (int i = 0; i < mm; i++) {
            int s = __shfl(e, (half << 5) + i);
            if (base + i < n) {            // uniform within half
                uint2 p = *(const uint2*)(h1s + s * 128 + l * 4);
                a0 += bflo(p.x); a1 += bfhi(p.x);
                a2 += bflo(p.y); a3 += bfhi(p.y);
            }
        }
    }
    float di = dinv[v];
    float4 bb = *(const float4*)(b1 + l * 4);
    a0 = fmaxf(fmaf(di, a0, bb.x), 0.f);
    a1 = fmaxf(fmaf(di, a1, bb.y), 0.f);
    a2 = fmaxf(fmaf(di, a2, bb.z), 0.f);
    a3 = fmaxf(fmaf(di, a3, bb.w), 0.f);
    uint2 o;
    o.x = (uint32_t)f2b(a0) | ((uint32_t)f2b(a1) << 16);
    o.y = (uint32_t)f2b(a2) | ((uint32_t)f2b(a3) << 16);
    *(uint2*)(r1b + v * 128 + l * 4) = o;
}

// ---------- 6. GEMM2: h2s[v] = dinv[v] * (r1b[v] @ W2)  (bf16 out) ----------
__global__ __launch_bounds__(256) void k_gemm2(const unsigned short* __restrict__ r1b,
                                               const float* __restrict__ W2,
                                               const float* __restrict__ dinv,
                                               unsigned short* __restrict__ h2s) {
    __shared__ float Wf[64 * 64];   // 16 KB
    __shared__ float xT[64 * 64];   // 16 KB
    int t = threadIdx.x;
    int row0 = blockIdx.x * 64;
    int tx = t & 15, ty = t >> 4;
    float acc[4][4] = {};
    for (int kh = 0; kh < 2; kh++) {
        int kbase = kh * 64;
        for (int c = t; c < 1024; c += 256) {
            *(float4*)&Wf[c * 4] = *(const float4*)(W2 + kbase * 64 + c * 4);
        }
        for (int c = t; c < 512; c += 256) {
            int r = c >> 3, kc = (c & 7) * 8;
            int grow = row0 + r; if (grow >= N_NODES) grow = N_NODES - 1;
            uint4 p = *(const uint4*)(r1b + grow * 128 + kbase + kc);
            xT[(kc + 0) * 64 + r] = bflo(p.x); xT[(kc + 1) * 64 + r] = bfhi(p.x);
            xT[(kc + 2) * 64 + r] = bflo(p.y); xT[(kc + 3) * 64 + r] = bfhi(p.y);
            xT[(kc + 4) * 64 + r] = bflo(p.z); xT[(kc + 5) * 64 + r] = bfhi(p.z);
            xT[(kc + 6) * 64 + r] = bflo(p.w); xT[(kc + 7) * 64 + r] = bfhi(p.w);
        }
        __syncthreads();
        #pragma unroll 8
        for (int k = 0; k < 64; k++) {
            float4 a  = *(const float4*)&xT[k * 64 + ty * 4];
            float4 wv = *(const float4*)&Wf[k * 64 + tx * 4];
            acc[0][0]=fmaf(a.x,wv.x,acc[0][0]); acc[0][1]=fmaf(a.x,wv.y,acc[0][1]); acc[0][2]=fmaf(a.x,wv.z,acc[0][2]); acc[0][3]=fmaf(a.x,wv.w,acc[0][3]);
            acc[1][0]=fmaf(a.y,wv.x,acc[1][0]); acc[1][1]=fmaf(a.y,wv.y,acc[1][1]); acc[1][2]=fmaf(a.y,wv.z,acc[1][2]); acc[1][3]=fmaf(a.y,wv.w,acc[1][3]);
            acc[2][0]=fmaf(a.z,wv.x,acc[2][0]); acc[2][1]=fmaf(a.z,wv.y,acc[2][1]); acc[2][2]=fmaf(a.z,wv.z,acc[2][2]); acc[2][3]=fmaf(a.z,wv.w,acc[2][3]);
            acc[3][0]=fmaf(a.w,wv.x,acc[3][0]); acc[3][1]=fmaf(a.w,wv.y,acc[3][1]); acc[3][2]=fmaf(a.w,wv.z,acc[3][2]); acc[3][3]=fmaf(a.w,wv.w,acc[3][3]);
        }
        __syncthreads();
    }
    #pragma unroll
    for (int i = 0; i < 4; i++) {
        int row = row0 + ty * 4 + i;
        if (row < N_NODES) {
            float di = dinv[row];
            uint2 o;
            o.x = (uint32_t)f2b(di * acc[i][0]) | ((uint32_t)f2b(di * acc[i][1]) << 16);
            o.y = (uint32_t)f2b(di * acc[i][2]) | ((uint32_t)f2b(di * acc[i][3]) << 16);
            *(uint2*)(h2s + row * 64 + tx * 4) = o;
        }
    }
}

// ---------- 7. agg2 + head: h3 = relu(dinv*Σ h2s + b2); out = log_softmax(h3@Wo+bo)
// 2 nodes per wave; each lane covers 2 bf16 cols (4 B) of its node's 128 B row.
__global__ __launch_bounds__(256) void k_agg2(const unsigned short* __restrict__ h2s,
                                              const int* __restrict__ csr_s,
                                              const int* __restrict__ offs,
                                              const int* __restrict__ counts,
                                              const float* __restrict__ dinv,
                                              const float* __restrict__ b2,
                                              const float* __restrict__ Wo,
                                              const float* __restrict__ bo,
                                              float* __restrict__ out) {
    int wave = (blockIdx.x * 256 + threadIdx.x) >> 6;
    int lane = threadIdx.x & 63;
    int half = lane >> 5, l = lane & 31;
    int v = wave * 2 + half;
    if (v >= N_NODES) return;
    int start = offs[v], n = counts[v];
    const int* cs = csr_s + start;
    int nmax = max(n, __shfl(n, lane ^ 32));
    float a0, a1;
    {
        uint32_t p = *(const uint32_t*)(h2s + v * 64 + l * 2);
        a0 = bflo(p); a1 = bfhi(p);
    }
    for (int base = 0; base < nmax; base += 32) {
        int idx = base + l;
        int e = (idx < n) ? cs[idx] : 0;
        int mm = nmax - base; if (mm > 32) mm = 32;
        #pragma unroll 4
        for (int i = 0; i < mm; i++) {
            int s = __shfl(e, (half << 5) + i);
            if (base + i < n) {
                uint32_t p = *(const uint32_t*)(h2s + s * 64 + l * 2);
                a0 += bflo(p); a1 += bfhi(p);
            }
        }
    }
    float di = dinv[v];
    float2 bb = *(const float2*)(b2 + l * 2);
    a0 = fmaxf(fmaf(di, a0, bb.x), 0.f);   // h3[2l]
    a1 = fmaxf(fmaf(di, a1, bb.y), 0.f);   // h3[2l+1]
    float4 wv = *(const float4*)(Wo + l * 4);  // rows 2l (x,y), 2l+1 (z,w)
    float l0 = a0 * wv.x + a1 * wv.z;
    float l1 = a0 * wv.y + a1 * wv.w;
    #pragma unroll
    for (int off = 16; off > 0; off >>= 1) {   // reduce within 32-lane half
        l0 += __shfl_xor(l0, off);
        l1 += __shfl_xor(l1, off);
    }
    if (l == 0) {
        float2 bof = *(const float2*)bo;
        l0 += bof.x; l1 += bof.y;
        float m = fmaxf(l0, l1);
        float ls = m + __logf(__expf(l0 - m) + __expf(l1 - m));
        *(float2*)(out + v * 2) = make_float2(l0 - ls, l1 - ls);
    }
}

extern "C" void kernel_launch(void* const* d_in, const int* in_sizes, int n_in,
                              void* d_out, int out_size, void* d_ws, size_t ws_size,
                              hipStream_t stream) {
    const float* x  = (const float*)d_in[0];
    const int* ei   = (const int*)d_in[1];
    const float* W1 = (const float*)d_in[2];
    const float* b1 = (const float*)d_in[3];
    const float* W2 = (const float*)d_in[4];
    const float* b2 = (const float*)d_in[5];
    const float* Wo = (const float*)d_in[6];
    const float* bo = (const float*)d_in[7];
    float* out      = (float*)d_out;
    const int* src = ei;             // edge_index[0]
    const int* dst = ei + N_EDGES;   // edge_index[1]

    char* w = (char*)d_ws;
    int*   counts = (int*)(w + 0);          // 200 KB
    int*   offs   = (int*)(w + 200704);     // 200 KB
    int*   cursor = (int*)(w + 401408);     // 200 KB
    int*   bsums  = (int*)(w + 602112);     // 1 KB
    float* dinv   = (float*)(w + 603136);   // 200 KB
    int*   csr_s  = (int*)(w + 803840);     // 3.2 MB (src only)
    unsigned short* h1s = (unsigned short*)(w + 4003840);   // 12.8 MB
    unsigned short* r1b = (unsigned short*)(w + 16803840);  // 12.8 MB
    unsigned short* h2s = (unsigned short*)(w + 29603840);  // 6.4 MB
    // total ws usage: ~36 MB

    hipMemsetAsync(counts, 0, N_NODES * sizeof(int), stream);
    hipMemsetAsync(cursor, 0, N_NODES * sizeof(int), stream);

    int nb = (N_NODES + 255) / 256;
    k_count  <<<(N_EDGES + 255) / 256, 256, 0, stream>>>(dst, counts);
    k_scan1  <<<nb, 256, 0, stream>>>(counts, offs, bsums, dinv);
    k_scan2  <<<1, 256, 0, stream>>>(bsums, nb);
    k_scan3  <<<nb, 256, 0, stream>>>(offs, bsums);
    k_scatter<<<(N_EDGES + 255) / 256, 256, 0, stream>>>(src, dst, offs, cursor, csr_s);

    k_gemm1  <<<(N_NODES + 31) / 32, 256, 0, stream>>>(x, W1, dinv, h1s);
    k_agg1   <<<(N_NODES + 7) / 8, 256, 0, stream>>>(h1s, csr_s, offs, counts, dinv, b1, r1b);
    k_gemm2  <<<(N_NODES + 63) / 64, 256, 0, stream>>>(r1b, W2, dinv, h2s);
    k_agg2   <<<(N_NODES + 7) / 8, 256, 0, stream>>>(h2s, csr_s, offs, counts, dinv, b2, Wo, bo, out);
}

// Round 5
// 251.939 us; speedup vs baseline: 1.5602x; 1.1540x over previous
//
#include <hip/hip_runtime.h>
#include <stdint.h>

#define N_NODES 50000
#define N_EDGES 800000
// D_IN=128, H1=128, H2=64, C=2 — inputs fp32; intermediates bf16 (dinv-prescaled rows)

// ---------- bf16 helpers ----------
__device__ __forceinline__ float bflo(uint32_t u) { return __uint_as_float(u << 16); }
__device__ __forceinline__ float bfhi(uint32_t u) { return __uint_as_float(u & 0xffff0000u); }
__device__ __forceinline__ unsigned short f2b(float f) {
    uint32_t u = __float_as_uint(f);
    u += 0x7fffu + ((u >> 16) & 1u);   // RNE
    return (unsigned short)(u >> 16);
}

// ---------- 1. in-degree count + per-edge rank (atomicAdd return) ----------
__global__ void k_count(const int* __restrict__ dst, int* __restrict__ counts,
                        int* __restrict__ rank) {
    int e = blockIdx.x * 256 + threadIdx.x;
    if (e < N_EDGES) {
        int d = dst[e];
        int r = 0;
        if ((unsigned)d < N_NODES) r = atomicAdd(&counts[d], 1);
        rank[e] = r;
    }
}

// ---------- 2a. per-block exclusive scan of counts (+ dinv fused) ----------
__global__ void k_scan1(const int* __restrict__ counts, int* __restrict__ offs,
                        int* __restrict__ bsums, float* __restrict__ dinv) {
    int t = threadIdx.x, b = blockIdx.x;
    int idx = b * 256 + t;
    int c = (idx < N_NODES) ? counts[idx] : 0;
    if (idx < N_NODES) dinv[idx] = rsqrtf((float)c + 1.0f);
    int v = c;
    int lane = t & 63, w = t >> 6;
    #pragma unroll
    for (int off = 1; off < 64; off <<= 1) {
        int u = __shfl_up(v, off);
        if (lane >= off) v += u;
    }
    __shared__ int wt[4];
    if (lane == 63) wt[w] = v;
    __syncthreads();
    int base = 0;
    for (int j = 0; j < w; j++) base += wt[j];
    if (idx < N_NODES) offs[idx] = base + v - c;
    if (t == 255) bsums[b] = base + v;
}

// ---------- 2b. exclusive scan of block sums (nb <= 256) ----------
__global__ void k_scan2(int* __restrict__ bsums, int nb) {
    int t = threadIdx.x;
    int c = (t < nb) ? bsums[t] : 0;
    int v = c;
    int lane = t & 63, w = t >> 6;
    #pragma unroll
    for (int off = 1; off < 64; off <<= 1) {
        int u = __shfl_up(v, off);
        if (lane >= off) v += u;
    }
    __shared__ int wt[4];
    if (lane == 63) wt[w] = v;
    __syncthreads();
    int base = 0;
    for (int j = 0; j < w; j++) base += wt[j];
    if (t < nb) bsums[t] = base + v - c;
}

// ---------- 2c. add block bases ----------
__global__ void k_scan3(int* __restrict__ offs, const int* __restrict__ bsums) {
    int idx = blockIdx.x * 256 + threadIdx.x;
    if (idx < N_NODES) offs[idx] += bsums[idx >> 8];
}

// ---------- 3. atomic-free scatter: csr_s[offs[d]+rank[e]] = s ----------
__global__ void k_scatter(const int* __restrict__ src, const int* __restrict__ dst,
                          const int* __restrict__ rank, const int* __restrict__ offs,
                          int* __restrict__ csr_s) {
    int e = blockIdx.x * 256 + threadIdx.x;
    if (e >= N_EDGES) return;
    int s = src[e], d = dst[e];
    if ((unsigned)s >= N_NODES || (unsigned)d >= N_NODES) return;
    csr_s[offs[d] + rank[e]] = s;
}

// ---------- 4. GEMM1: h1s[v] = dinv[v] * (x[v] @ W1)  (bf16 out) ----------
__global__ __launch_bounds__(256) void k_gemm1(const float* __restrict__ x,
                                               const float* __restrict__ W1,
                                               const float* __restrict__ dinv,
                                               unsigned short* __restrict__ h1s) {
    __shared__ float Wf[64 * 128];  // 32 KB
    __shared__ float xT[64 * 32];   // 8 KB
    int t = threadIdx.x;
    int row0 = blockIdx.x * 32;
    int tx = t & 31, ty = t >> 5;
    float acc[4][4] = {};
    for (int kh = 0; kh < 2; kh++) {
        int kbase = kh * 64;
        for (int c = t; c < 2048; c += 256) {
            *(float4*)&Wf[c * 4] = *(const float4*)(W1 + kbase * 128 + c * 4);
        }
        {
            int r = t >> 3, kc = (t & 7) * 8;
            int grow = row0 + r; if (grow >= N_NODES) grow = N_NODES - 1;
            const float* p = x + grow * 128 + kbase + kc;
            float4 a = *(const float4*)p;
            float4 b = *(const float4*)(p + 4);
            xT[(kc + 0) * 32 + r] = a.x; xT[(kc + 1) * 32 + r] = a.y;
            xT[(kc + 2) * 32 + r] = a.z; xT[(kc + 3) * 32 + r] = a.w;
            xT[(kc + 4) * 32 + r] = b.x; xT[(kc + 5) * 32 + r] = b.y;
            xT[(kc + 6) * 32 + r] = b.z; xT[(kc + 7) * 32 + r] = b.w;
        }
        __syncthreads();
        #pragma unroll 8
        for (int k = 0; k < 64; k++) {
            float4 a  = *(const float4*)&xT[k * 32 + ty * 4];
            float4 wv = *(const float4*)&Wf[k * 128 + tx * 4];
            acc[0][0]=fmaf(a.x,wv.x,acc[0][0]); acc[0][1]=fmaf(a.x,wv.y,acc[0][1]); acc[0][2]=fmaf(a.x,wv.z,acc[0][2]); acc[0][3]=fmaf(a.x,wv.w,acc[0][3]);
            acc[1][0]=fmaf(a.y,wv.x,acc[1][0]); acc[1][1]=fmaf(a.y,wv.y,acc[1][1]); acc[1][2]=fmaf(a.y,wv.z,acc[1][2]); acc[1][3]=fmaf(a.y,wv.w,acc[1][3]);
            acc[2][0]=fmaf(a.z,wv.x,acc[2][0]); acc[2][1]=fmaf(a.z,wv.y,acc[2][1]); acc[2][2]=fmaf(a.z,wv.z,acc[2][2]); acc[2][3]=fmaf(a.z,wv.w,acc[2][3]);
            acc[3][0]=fmaf(a.w,wv.x,acc[3][0]); acc[3][1]=fmaf(a.w,wv.y,acc[3][1]); acc[3][2]=fmaf(a.w,wv.z,acc[3][2]); acc[3][3]=fmaf(a.w,wv.w,acc[3][3]);
        }
        __syncthreads();
    }
    #pragma unroll
    for (int i = 0; i < 4; i++) {
        int row = row0 + ty * 4 + i;
        if (row < N_NODES) {
            float di = dinv[row];
            uint2 o;
            o.x = (uint32_t)f2b(di * acc[i][0]) | ((uint32_t)f2b(di * acc[i][1]) << 16);
            o.y = (uint32_t)f2b(di * acc[i][2]) | ((uint32_t)f2b(di * acc[i][3]) << 16);
            *(uint2*)(h1s + row * 128 + tx * 4) = o;
        }
    }
}

// ---------- 5. agg1: r1b[v] = relu(dinv[v]*Σ_{s∈N(v)∪{v}} h1s[s] + b1) ----------
// 4 nodes per wave: quarter q = lane>>4 serves node v = 4w+q; lane covers 8 bf16
// cols (16 B) of its node's 256 B row — 1 KB in flight per gather instruction.
__global__ __launch_bounds__(256) void k_agg1(const unsigned short* __restrict__ h1s,
                                              const int* __restrict__ csr_s,
                                              const int* __restrict__ offs,
                                              const int* __restrict__ counts,
                                              const float* __restrict__ dinv,
                                              const float* __restrict__ b1,
                                              unsigned short* __restrict__ r1b) {
    int wave = (blockIdx.x * 256 + threadIdx.x) >> 6;
    int lane = threadIdx.x & 63;
    int q = lane >> 4, l = lane & 15;
    int v = wave * 4 + q;
    bool valid = v < N_NODES;
    int vv = valid ? v : N_NODES - 1;
    int start = offs[vv];
    int n = valid ? counts[vv] : 0;
    const int* cs = csr_s + start;
    int nmax = n;
    nmax = max(nmax, __shfl_xor(nmax, 16));
    nmax = max(nmax, __shfl_xor(nmax, 32));
    float a0, a1, a2, a3, a4, a5, a6, a7;
    {   // self-loop row
        uint4 p = *(const uint4*)(h1s + vv * 128 + l * 8);
        a0 = bflo(p.x); a1 = bfhi(p.x); a2 = bflo(p.y); a3 = bfhi(p.y);
        a4 = bflo(p.z); a5 = bfhi(p.z); a6 = bflo(p.w); a7 = bfhi(p.w);
    }
    for (int base = 0; base < nmax; base += 16) {
        int idx = base + l;
        int e = (idx < n) ? cs[idx] : 0;     // coalesced per quarter
        int mm = nmax - base; if (mm > 16) mm = 16;
        #pragma unroll 4
        for (int i = 0; i < mm; i++) {
            int s = __shfl(e, (q << 4) + i);
            if (base + i < n) {              // uniform within quarter
                uint4 p = *(const uint4*)(h1s + s * 128 + l * 8);
                a0 += bflo(p.x); a1 += bfhi(p.x); a2 += bflo(p.y); a3 += bfhi(p.y);
                a4 += bflo(p.z); a5 += bfhi(p.z); a6 += bflo(p.w); a7 += bfhi(p.w);
            }
        }
    }
    if (!valid) return;
    float di = dinv[v];
    float4 bL = *(const float4*)(b1 + l * 8);
    float4 bH = *(const float4*)(b1 + l * 8 + 4);
    a0 = fmaxf(fmaf(di, a0, bL.x), 0.f); a1 = fmaxf(fmaf(di, a1, bL.y), 0.f);
    a2 = fmaxf(fmaf(di, a2, bL.z), 0.f); a3 = fmaxf(fmaf(di, a3, bL.w), 0.f);
    a4 = fmaxf(fmaf(di, a4, bH.x), 0.f); a5 = fmaxf(fmaf(di, a5, bH.y), 0.f);
    a6 = fmaxf(fmaf(di, a6, bH.z), 0.f); a7 = fmaxf(fmaf(di, a7, bH.w), 0.f);
    uint4 o;
    o.x = (uint32_t)f2b(a0) | ((uint32_t)f2b(a1) << 16);
    o.y = (uint32_t)f2b(a2) | ((uint32_t)f2b(a3) << 16);
    o.z = (uint32_t)f2b(a4) | ((uint32_t)f2b(a5) << 16);
    o.w = (uint32_t)f2b(a6) | ((uint32_t)f2b(a7) << 16);
    *(uint4*)(r1b + v * 128 + l * 8) = o;
}

// ---------- 6. GEMM2: h2s[v] = dinv[v] * (r1b[v] @ W2)  (bf16 out) ----------
__global__ __launch_bounds__(256) void k_gemm2(const unsigned short* __restrict__ r1b,
                                               const float* __restrict__ W2,
                                               const float* __restrict__ dinv,
                                               unsigned short* __restrict__ h2s) {
    __shared__ float Wf[64 * 64];   // 16 KB
    __shared__ float xT[64 * 64];   // 16 KB
    int t = threadIdx.x;
    int row0 = blockIdx.x * 64;
    int tx = t & 15, ty = t >> 4;
    float acc[4][4] = {};
    for (int kh = 0; kh < 2; kh++) {
        int kbase = kh * 64;
        for (int c = t; c < 1024; c += 256) {
            *(float4*)&Wf[c * 4] = *(const float4*)(W2 + kbase * 64 + c * 4);
        }
        for (int c = t; c < 512; c += 256) {
            int r = c >> 3, kc = (c & 7) * 8;
            int grow = row0 + r; if (grow >= N_NODES) grow = N_NODES - 1;
            uint4 p = *(const uint4*)(r1b + grow * 128 + kbase + kc);
            xT[(kc + 0) * 64 + r] = bflo(p.x); xT[(kc + 1) * 64 + r] = bfhi(p.x);
            xT[(kc + 2) * 64 + r] = bflo(p.y); xT[(kc + 3) * 64 + r] = bfhi(p.y);
            xT[(kc + 4) * 64 + r] = bflo(p.z); xT[(kc + 5) * 64 + r] = bfhi(p.z);
            xT[(kc + 6) * 64 + r] = bflo(p.w); xT[(kc + 7) * 64 + r] = bfhi(p.w);
        }
        __syncthreads();
        #pragma unroll 8
        for (int k = 0; k < 64; k++) {
            float4 a  = *(const float4*)&xT[k * 64 + ty * 4];
            float4 wv = *(const float4*)&Wf[k * 64 + tx * 4];
            acc[0][0]=fmaf(a.x,wv.x,acc[0][0]); acc[0][1]=fmaf(a.x,wv.y,acc[0][1]); acc[0][2]=fmaf(a.x,wv.z,acc[0][2]); acc[0][3]=fmaf(a.x,wv.w,acc[0][3]);
            acc[1][0]=fmaf(a.y,wv.x,acc[1][0]); acc[1][1]=fmaf(a.y,wv.y,acc[1][1]); acc[1][2]=fmaf(a.y,wv.z,acc[1][2]); acc[1][3]=fmaf(a.y,wv.w,acc[1][3]);
            acc[2][0]=fmaf(a.z,wv.x,acc[2][0]); acc[2][1]=fmaf(a.z,wv.y,acc[2][1]); acc[2][2]=fmaf(a.z,wv.z,acc[2][2]); acc[2][3]=fmaf(a.z,wv.w,acc[2][3]);
            acc[3][0]=fmaf(a.w,wv.x,acc[3][0]); acc[3][1]=fmaf(a.w,wv.y,acc[3][1]); acc[3][2]=fmaf(a.w,wv.z,acc[3][2]); acc[3][3]=fmaf(a.w,wv.w,acc[3][3]);
        }
        __syncthreads();
    }
    #pragma unroll
    for (int i = 0; i < 4; i++) {
        int row = row0 + ty * 4 + i;
        if (row < N_NODES) {
            float di = dinv[row];
            uint2 o;
            o.x = (uint32_t)f2b(di * acc[i][0]) | ((uint32_t)f2b(di * acc[i][1]) << 16);
            o.y = (uint32_t)f2b(di * acc[i][2]) | ((uint32_t)f2b(di * acc[i][3]) << 16);
            *(uint2*)(h2s + row * 64 + tx * 4) = o;
        }
    }
}

// ---------- 7. agg2 + head: h3 = relu(dinv*Σ h2s + b2); out = log_softmax(h3@Wo+bo)
// 4 nodes per wave; lane covers 4 bf16 cols (8 B) of its node's 128 B row.
__global__ __launch_bounds__(256) void k_agg2(const unsigned short* __restrict__ h2s,
                                              const int* __restrict__ csr_s,
                                              const int* __restrict__ offs,
                                              const int* __restrict__ counts,
                                              const float* __restrict__ dinv,
                                              const float* __restrict__ b2,
                                              const float* __restrict__ Wo,
                                              const float* __restrict__ bo,
                                              float* __restrict__ out) {
    int wave = (blockIdx.x * 256 + threadIdx.x) >> 6;
    int lane = threadIdx.x & 63;
    int q = lane >> 4, l = lane & 15;
    int v = wave * 4 + q;
    bool valid = v < N_NODES;
    int vv = valid ? v : N_NODES - 1;
    int start = offs[vv];
    int n = valid ? counts[vv] : 0;
    const int* cs = csr_s + start;
    int nmax = n;
    nmax = max(nmax, __shfl_xor(nmax, 16));
    nmax = max(nmax, __shfl_xor(nmax, 32));
    float a0, a1, a2, a3;
    {
        uint2 p = *(const uint2*)(h2s + vv * 64 + l * 4);
        a0 = bflo(p.x); a1 = bfhi(p.x); a2 = bflo(p.y); a3 = bfhi(p.y);
    }
    for (int base = 0; base < nmax; base += 16) {
        int idx = base + l;
        int e = (idx < n) ? cs[idx] : 0;
        int mm = nmax - base; if (mm > 16) mm = 16;
        #pragma unroll 4
        for (int i = 0; i < mm; i++) {
            int s = __shfl(e, (q << 4) + i);
            if (base + i < n) {
                uint2 p = *(const uint2*)(h2s + s * 64 + l * 4);
                a0 += bflo(p.x); a1 += bfhi(p.x); a2 += bflo(p.y); a3 += bfhi(p.y);
            }
        }
    }
    float di = valid ? dinv[vv] : 0.f;
    float4 bb = *(const float4*)(b2 + l * 4);
    a0 = fmaxf(fmaf(di, a0, bb.x), 0.f);   // h3[4l+0]
    a1 = fmaxf(fmaf(di, a1, bb.y), 0.f);   // h3[4l+1]
    a2 = fmaxf(fmaf(di, a2, bb.z), 0.f);   // h3[4l+2]
    a3 = fmaxf(fmaf(di, a3, bb.w), 0.f);   // h3[4l+3]
    float4 w01 = *(const float4*)(Wo + l * 8);      // rows 4l, 4l+1
    float4 w23 = *(const float4*)(Wo + l * 8 + 4);  // rows 4l+2, 4l+3
    float l0 = a0 * w01.x + a1 * w01.z + a2 * w23.x + a3 * w23.z;
    float l1 = a0 * w01.y + a1 * w01.w + a2 * w23.y + a3 * w23.w;
    #pragma unroll
    for (int off = 8; off > 0; off >>= 1) {   // reduce within 16-lane quarter
        l0 += __shfl_xor(l0, off);
        l1 += __shfl_xor(l1, off);
    }
    if (l == 0 && valid) {
        float2 bof = *(const float2*)bo;
        l0 += bof.x; l1 += bof.y;
        float m = fmaxf(l0, l1);
        float ls = m + __logf(__expf(l0 - m) + __expf(l1 - m));
        *(float2*)(out + v * 2) = make_float2(l0 - ls, l1 - ls);
    }
}

extern "C" void kernel_launch(void* const* d_in, const int* in_sizes, int n_in,
                              void* d_out, int out_size, void* d_ws, size_t ws_size,
                              hipStream_t stream) {
    const float* x  = (const float*)d_in[0];
    const int* ei   = (const int*)d_in[1];
    const float* W1 = (const float*)d_in[2];
    const float* b1 = (const float*)d_in[3];
    const float* W2 = (const float*)d_in[4];
    const float* b2 = (const float*)d_in[5];
    const float* Wo = (const float*)d_in[6];
    const float* bo = (const float*)d_in[7];
    float* out      = (float*)d_out;
    const int* src = ei;             // edge_index[0]
    const int* dst = ei + N_EDGES;   // edge_index[1]

    char* w = (char*)d_ws;
    int*   counts = (int*)(w + 0);          // 200 KB
    int*   offs   = (int*)(w + 200704);     // 200 KB
    int*   bsums  = (int*)(w + 401408);     // 1 KB
    float* dinv   = (float*)(w + 402432);   // 200 KB
    int*   rank   = (int*)(w + 602432);     // 3.2 MB
    int*   csr_s  = (int*)(w + 3802432);    // 3.2 MB
    unsigned short* h1s = (unsigned short*)(w + 7002432);   // 12.8 MB (16B-aligned)
    unsigned short* r1b = (unsigned short*)(w + 19802432);  // 12.8 MB
    unsigned short* h2s = (unsigned short*)(w + 32602432);  // 6.4 MB
    // total ws usage: ~39 MB

    hipMemsetAsync(counts, 0, N_NODES * sizeof(int), stream);

    int nb = (N_NODES + 255) / 256;
    k_count  <<<(N_EDGES + 255) / 256, 256, 0, stream>>>(dst, counts, rank);
    k_scan1  <<<nb, 256, 0, stream>>>(counts, offs, bsums, dinv);
    k_scan2  <<<1, 256, 0, stream>>>(bsums, nb);
    k_scan3  <<<nb, 256, 0, stream>>>(offs, bsums);
    k_scatter<<<(N_EDGES + 255) / 256, 256, 0, stream>>>(src, dst, rank, offs, csr_s);

    k_gemm1  <<<(N_NODES + 31) / 32, 256, 0, stream>>>(x, W1, dinv, h1s);
    k_agg1   <<<(N_NODES + 15) / 16, 256, 0, stream>>>(h1s, csr_s, offs, counts, dinv, b1, r1b);
    k_gemm2  <<<(N_NODES + 63) / 64, 256, 0, stream>>>(r1b, W2, dinv, h2s);
    k_agg2   <<<(N_NODES + 15) / 16, 256, 0, stream>>>(h2s, csr_s, offs, counts, dinv, b2, Wo, bo, out);
}

// Round 6
// 209.660 us; speedup vs baseline: 1.8748x; 1.2017x over previous
//
#include <hip/hip_runtime.h>
#include <stdint.h>

#define N_NODES 50000
#define N_EDGES 800000
// D_IN=128, H1=128, H2=64, C=2 — inputs fp32; intermediates bf16 (dinv-prescaled)

typedef __attribute__((ext_vector_type(8))) short short8;     // 8 bf16 (4 VGPRs)
typedef __attribute__((ext_vector_type(4))) float floatx4;    // MFMA acc

// ---------- bf16 helpers ----------
__device__ __forceinline__ float bflo(uint32_t u) { return __uint_as_float(u << 16); }
__device__ __forceinline__ float bfhi(uint32_t u) { return __uint_as_float(u & 0xffff0000u); }
__device__ __forceinline__ unsigned short f2b(float f) {
    uint32_t u = __float_as_uint(f);
    u += 0x7fffu + ((u >> 16) & 1u);   // RNE
    return (unsigned short)(u >> 16);
}

// ---------- 1. in-degree count + per-edge rank (atomicAdd return) ----------
__global__ void k_count(const int* __restrict__ dst, int* __restrict__ counts,
                        int* __restrict__ rank) {
    int e = blockIdx.x * 256 + threadIdx.x;
    if (e < N_EDGES) {
        int d = dst[e];
        int r = 0;
        if ((unsigned)d < N_NODES) r = atomicAdd(&counts[d], 1);
        rank[e] = r;
    }
}

// ---------- 2a. per-block exclusive scan of counts (+ dinv fused) ----------
__global__ void k_scan1(const int* __restrict__ counts, int* __restrict__ offs,
                        int* __restrict__ bsums, float* __restrict__ dinv) {
    int t = threadIdx.x, b = blockIdx.x;
    int idx = b * 256 + t;
    int c = (idx < N_NODES) ? counts[idx] : 0;
    if (idx < N_NODES) dinv[idx] = rsqrtf((float)c + 1.0f);
    int v = c;
    int lane = t & 63, w = t >> 6;
    #pragma unroll
    for (int off = 1; off < 64; off <<= 1) {
        int u = __shfl_up(v, off);
        if (lane >= off) v += u;
    }
    __shared__ int wt[4];
    if (lane == 63) wt[w] = v;
    __syncthreads();
    int base = 0;
    for (int j = 0; j < w; j++) base += wt[j];
    if (idx < N_NODES) offs[idx] = base + v - c;
    if (t == 255) bsums[b] = base + v;
}

// ---------- 2b. exclusive scan of block sums (nb <= 256) ----------
__global__ void k_scan2(int* __restrict__ bsums, int nb) {
    int t = threadIdx.x;
    int c = (t < nb) ? bsums[t] : 0;
    int v = c;
    int lane = t & 63, w = t >> 6;
    #pragma unroll
    for (int off = 1; off < 64; off <<= 1) {
        int u = __shfl_up(v, off);
        if (lane >= off) v += u;
    }
    __shared__ int wt[4];
    if (lane == 63) wt[w] = v;
    __syncthreads();
    int base = 0;
    for (int j = 0; j < w; j++) base += wt[j];
    if (t < nb) bsums[t] = base + v - c;
}

// ---------- 2c. add block bases + W1/W2 transpose-convert (fold into idle lanes)
__global__ void k_scan3(int* __restrict__ offs, const int* __restrict__ bsums,
                        const float* __restrict__ W1, const float* __restrict__ W2,
                        unsigned short* __restrict__ Wt1, unsigned short* __restrict__ Wt2) {
    int gid = blockIdx.x * 256 + threadIdx.x;
    if (gid < N_NODES) offs[gid] += bsums[gid >> 8];
    if (gid < 16384) {                    // Wt1[n][k] = bf16(W1[k][n])
        int k = gid >> 7, n = gid & 127;
        Wt1[n * 128 + k] = f2b(W1[gid]);
    } else if (gid < 24576) {             // Wt2[n][k] = bf16(W2[k][n])
        int j = gid - 16384;
        int k = j >> 6, n = j & 63;
        Wt2[n * 128 + k] = f2b(W2[j]);
    }
}

// ---------- 3. atomic-free scatter: csr_s[offs[d]+rank[e]] = s ----------
__global__ void k_scatter(const int* __restrict__ src, const int* __restrict__ dst,
                          const int* __restrict__ rank, const int* __restrict__ offs,
                          int* __restrict__ csr_s) {
    int e = blockIdx.x * 256 + threadIdx.x;
    if (e >= N_EDGES) return;
    int s = src[e], d = dst[e];
    if ((unsigned)s >= N_NODES || (unsigned)d >= N_NODES) return;
    csr_s[offs[d] + rank[e]] = s;
}

// ---------- 4. MFMA GEMM1: h1s[v] = dinv[v] * bf16(x[v]) @ bf16(W1)  ----------
// 64 rows/block, full K=128 in LDS. A: At[64][136] bf16; B: Bt[128][136] bf16.
// Wave w -> rows 16w..16w+15; 8 col-tiles of 16; 4 K-steps of 32.
__global__ __launch_bounds__(256) void k_gemm1(const float* __restrict__ x,
                                               const unsigned short* __restrict__ Wt1,
                                               const float* __restrict__ dinv,
                                               unsigned short* __restrict__ h1s) {
    __shared__ unsigned short At[64 * 136];   // 17.0 KB (pad 8 bf16: 2-way max alias)
    __shared__ unsigned short Bt[128 * 136];  // 34.0 KB
    int t = threadIdx.x;
    int row0 = blockIdx.x * 64;
    // stage Bt (Wt1 is [n][k] bf16, contiguous): 2048 chunks of 8
    for (int i = t; i < 2048; i += 256) {
        int n = i >> 4, kc = (i & 15) * 8;
        *(uint4*)&Bt[n * 136 + kc] = *(const uint4*)(Wt1 + n * 128 + kc);
    }
    // stage At: fp32 -> bf16, 1024 chunks of 8
    for (int i = t; i < 1024; i += 256) {
        int r = i >> 4, kc = (i & 15) * 8;
        int g = row0 + r; if (g >= N_NODES) g = N_NODES - 1;
        const float* p = x + g * 128 + kc;
        float4 a = *(const float4*)p, b = *(const float4*)(p + 4);
        uint4 o;
        o.x = (uint32_t)f2b(a.x) | ((uint32_t)f2b(a.y) << 16);
        o.y = (uint32_t)f2b(a.z) | ((uint32_t)f2b(a.w) << 16);
        o.z = (uint32_t)f2b(b.x) | ((uint32_t)f2b(b.y) << 16);
        o.w = (uint32_t)f2b(b.z) | ((uint32_t)f2b(b.w) << 16);
        *(uint4*)&At[r * 136 + kc] = o;
    }
    __syncthreads();
    int wv = t >> 6, lane = t & 63;
    int m = lane & 15, qd = lane >> 4;
    floatx4 acc[8];
    #pragma unroll
    for (int c = 0; c < 8; c++) acc[c] = (floatx4){0.f, 0.f, 0.f, 0.f};
    const unsigned short* ap = &At[(wv * 16 + m) * 136 + qd * 8];
    const unsigned short* bp = &Bt[m * 136 + qd * 8];
    #pragma unroll
    for (int kk = 0; kk < 4; kk++) {
        short8 af = *(const short8*)(ap + kk * 32);
        #pragma unroll
        for (int c = 0; c < 8; c++) {
            short8 bf = *(const short8*)(bp + c * 16 * 136 + kk * 32);
            acc[c] = __builtin_amdgcn_mfma_f32_16x16x32_bf16(af, bf, acc[c], 0, 0, 0);
        }
    }
    // epilogue: D[row=qd*4+reg][col=16c+m]
    #pragma unroll
    for (int reg = 0; reg < 4; reg++) {
        int g = row0 + wv * 16 + qd * 4 + reg;
        if (g < N_NODES) {
            float di = dinv[g];
            #pragma unroll
            for (int c = 0; c < 8; c++)
                h1s[g * 128 + c * 16 + m] = f2b(di * acc[c][reg]);
        }
    }
}

// ---------- 5. fused agg1 + GEMM2: ----------
// agg: r1[v] = relu(dinv[v]*Σ h1s[N(v)∪{v}] + b1) -> LDS A-tile (16 nodes/block)
// gemm: h2s[v] = dinv[v] * (r1 @ W2) via 1 MFMA col-tile per wave.
__global__ __launch_bounds__(256) void k_agg1g2(const unsigned short* __restrict__ h1s,
                                                const unsigned short* __restrict__ Wt2,
                                                const int* __restrict__ csr_s,
                                                const int* __restrict__ offs,
                                                const int* __restrict__ counts,
                                                const float* __restrict__ dinv,
                                                const float* __restrict__ b1,
                                                unsigned short* __restrict__ h2s) {
    __shared__ unsigned short Bt[64 * 136];   // Wt2 [n=64][k=128] staged
    __shared__ unsigned short At[16 * 136];   // r1 tile [16 rows][128 k]
    int t = threadIdx.x;
    for (int i = t; i < 1024; i += 256) {     // stage Bt2
        int n = i >> 4, kc = (i & 15) * 8;
        *(uint4*)&Bt[n * 136 + kc] = *(const uint4*)(Wt2 + n * 128 + kc);
    }
    int wv = t >> 6, lane = t & 63;
    int q = lane >> 4, l = lane & 15;
    int v0 = blockIdx.x * 16;
    int v = v0 + wv * 4 + q;                  // 50000 = 3125*16: always valid
    int vv = (v < N_NODES) ? v : N_NODES - 1;
    int start = offs[vv];
    int n = (v < N_NODES) ? counts[vv] : 0;
    const int* cs = csr_s + start;
    int nmax = n;
    nmax = max(nmax, __shfl_xor(nmax, 16));
    nmax = max(nmax, __shfl_xor(nmax, 32));
    float a0, a1, a2, a3, a4, a5, a6, a7;
    {   // self-loop row
        uint4 p = *(const uint4*)(h1s + vv * 128 + l * 8);
        a0 = bflo(p.x); a1 = bfhi(p.x); a2 = bflo(p.y); a3 = bfhi(p.y);
        a4 = bflo(p.z); a5 = bfhi(p.z); a6 = bflo(p.w); a7 = bfhi(p.w);
    }
    for (int base = 0; base < nmax; base += 16) {
        int idx = base + l;
        int e = (idx < n) ? cs[idx] : 0;      // coalesced per quarter
        int mm = nmax - base; if (mm > 16) mm = 16;
        #pragma unroll 4
        for (int i = 0; i < mm; i++) {
            int s = __shfl(e, (q << 4) + i);
            if (base + i < n) {               // uniform within quarter
                uint4 p = *(const uint4*)(h1s + s * 128 + l * 8);
                a0 += bflo(p.x); a1 += bfhi(p.x); a2 += bflo(p.y); a3 += bfhi(p.y);
                a4 += bflo(p.z); a5 += bfhi(p.z); a6 += bflo(p.w); a7 += bfhi(p.w);
            }
        }
    }
    {
        float di = dinv[vv];
        float4 bL = *(const float4*)(b1 + l * 8);
        float4 bH = *(const float4*)(b1 + l * 8 + 4);
        a0 = fmaxf(fmaf(di, a0, bL.x), 0.f); a1 = fmaxf(fmaf(di, a1, bL.y), 0.f);
        a2 = fmaxf(fmaf(di, a2, bL.z), 0.f); a3 = fmaxf(fmaf(di, a3, bL.w), 0.f);
        a4 = fmaxf(fmaf(di, a4, bH.x), 0.f); a5 = fmaxf(fmaf(di, a5, bH.y), 0.f);
        a6 = fmaxf(fmaf(di, a6, bH.z), 0.f); a7 = fmaxf(fmaf(di, a7, bH.w), 0.f);
        uint4 o;
        o.x = (uint32_t)f2b(a0) | ((uint32_t)f2b(a1) << 16);
        o.y = (uint32_t)f2b(a2) | ((uint32_t)f2b(a3) << 16);
        o.z = (uint32_t)f2b(a4) | ((uint32_t)f2b(a5) << 16);
        o.w = (uint32_t)f2b(a6) | ((uint32_t)f2b(a7) << 16);
        *(uint4*)&At[(wv * 4 + q) * 136 + l * 8] = o;   // r1 tile row
    }
    __syncthreads();
    // MFMA: wave wv -> col-tile wv (cols 16wv..16wv+15)
    int m = lane & 15, qd = lane >> 4;
    floatx4 acc = (floatx4){0.f, 0.f, 0.f, 0.f};
    const unsigned short* ap = &At[m * 136 + qd * 8];
    const unsigned short* bp = &Bt[(wv * 16 + m) * 136 + qd * 8];
    #pragma unroll
    for (int kk = 0; kk < 4; kk++) {
        short8 af = *(const short8*)(ap + kk * 32);
        short8 bf = *(const short8*)(bp + kk * 32);
        acc = __builtin_amdgcn_mfma_f32_16x16x32_bf16(af, bf, acc, 0, 0, 0);
    }
    #pragma unroll
    for (int reg = 0; reg < 4; reg++) {
        int g = v0 + qd * 4 + reg;
        if (g < N_NODES) {
            float di = dinv[g];
            h2s[g * 64 + wv * 16 + m] = f2b(di * acc[reg]);
        }
    }
}

// ---------- 6. agg2 + head: h3 = relu(dinv*Σ h2s + b2); out = log_softmax(h3@Wo+bo)
__global__ __launch_bounds__(256) void k_agg2(const unsigned short* __restrict__ h2s,
                                              const int* __restrict__ csr_s,
                                              const int* __restrict__ offs,
                                              const int* __restrict__ counts,
                                              const float* __restrict__ dinv,
                                              const float* __restrict__ b2,
                                              const float* __restrict__ Wo,
                                              const float* __restrict__ bo,
                                              float* __restrict__ out) {
    int wave = (blockIdx.x * 256 + threadIdx.x) >> 6;
    int lane = threadIdx.x & 63;
    int q = lane >> 4, l = lane & 15;
    int v = wave * 4 + q;
    bool valid = v < N_NODES;
    int vv = valid ? v : N_NODES - 1;
    int start = offs[vv];
    int n = valid ? counts[vv] : 0;
    const int* cs = csr_s + start;
    int nmax = n;
    nmax = max(nmax, __shfl_xor(nmax, 16));
    nmax = max(nmax, __shfl_xor(nmax, 32));
    float a0, a1, a2, a3;
    {
        uint2 p = *(const uint2*)(h2s + vv * 64 + l * 4);
        a0 = bflo(p.x); a1 = bfhi(p.x); a2 = bflo(p.y); a3 = bfhi(p.y);
    }
    for (int base = 0; base < nmax; base += 16) {
        int idx = base + l;
        int e = (idx < n) ? cs[idx] : 0;
        int mm = nmax - base; if (mm > 16) mm = 16;
        #pragma unroll 4
        for (int i = 0; i < mm; i++) {
            int s = __shfl(e, (q << 4) + i);
            if (base + i < n) {
                uint2 p = *(const uint2*)(h2s + s * 64 + l * 4);
                a0 += bflo(p.x); a1 += bfhi(p.x); a2 += bflo(p.y); a3 += bfhi(p.y);
            }
        }
    }
    float di = valid ? dinv[vv] : 0.f;
    float4 bb = *(const float4*)(b2 + l * 4);
    a0 = fmaxf(fmaf(di, a0, bb.x), 0.f);
    a1 = fmaxf(fmaf(di, a1, bb.y), 0.f);
    a2 = fmaxf(fmaf(di, a2, bb.z), 0.f);
    a3 = fmaxf(fmaf(di, a3, bb.w), 0.f);
    float4 w01 = *(const float4*)(Wo + l * 8);
    float4 w23 = *(const float4*)(Wo + l * 8 + 4);
    float l0 = a0 * w01.x + a1 * w01.z + a2 * w23.x + a3 * w23.z;
    float l1 = a0 * w01.y + a1 * w01.w + a2 * w23.y + a3 * w23.w;
    #pragma unroll
    for (int off = 8; off > 0; off >>= 1) {
        l0 += __shfl_xor(l0, off);
        l1 += __shfl_xor(l1, off);
    }
    if (l == 0 && valid) {
        float2 bof = *(const float2*)bo;
        l0 += bof.x; l1 += bof.y;
        float m = fmaxf(l0, l1);
        float ls = m + __logf(__expf(l0 - m) + __expf(l1 - m));
        *(float2*)(out + v * 2) = make_float2(l0 - ls, l1 - ls);
    }
}

extern "C" void kernel_launch(void* const* d_in, const int* in_sizes, int n_in,
                              void* d_out, int out_size, void* d_ws, size_t ws_size,
                              hipStream_t stream) {
    const float* x  = (const float*)d_in[0];
    const int* ei   = (const int*)d_in[1];
    const float* W1 = (const float*)d_in[2];
    const float* b1 = (const float*)d_in[3];
    const float* W2 = (const float*)d_in[4];
    const float* b2 = (const float*)d_in[5];
    const float* Wo = (const float*)d_in[6];
    const float* bo = (const float*)d_in[7];
    float* out      = (float*)d_out;
    const int* src = ei;             // edge_index[0]
    const int* dst = ei + N_EDGES;   // edge_index[1]

    char* w = (char*)d_ws;
    int*   counts = (int*)(w + 0);          // 200 KB
    int*   offs   = (int*)(w + 200704);     // 200 KB
    int*   bsums  = (int*)(w + 401408);     // 1 KB
    float* dinv   = (float*)(w + 402432);   // 200 KB
    int*   rank   = (int*)(w + 603136);     // 3.2 MB
    int*   csr_s  = (int*)(w + 3803136);    // 3.2 MB
    unsigned short* Wt1 = (unsigned short*)(w + 7003136);  // 32 KB  [n=128][k=128]
    unsigned short* Wt2 = (unsigned short*)(w + 7035904);  // 16 KB  [n=64][k=128]
    unsigned short* h1s = (unsigned short*)(w + 7052800);  // 12.8 MB
    unsigned short* h2s = (unsigned short*)(w + 19852800); // 6.4 MB
    // total ws usage: ~26.3 MB

    hipMemsetAsync(counts, 0, N_NODES * sizeof(int), stream);

    int nb = (N_NODES + 255) / 256;
    k_count  <<<(N_EDGES + 255) / 256, 256, 0, stream>>>(dst, counts, rank);
    k_scan1  <<<nb, 256, 0, stream>>>(counts, offs, bsums, dinv);
    k_scan2  <<<1, 256, 0, stream>>>(bsums, nb);
    k_scan3  <<<nb, 256, 0, stream>>>(offs, bsums, W1, W2, Wt1, Wt2);
    k_scatter<<<(N_EDGES + 255) / 256, 256, 0, stream>>>(src, dst, rank, offs, csr_s);

    k_gemm1  <<<(N_NODES + 63) / 64, 256, 0, stream>>>(x, Wt1, dinv, h1s);
    k_agg1g2 <<<(N_NODES + 15) / 16, 256, 0, stream>>>(h1s, Wt2, csr_s, offs, counts, dinv, b1, h2s);
    k_agg2   <<<(N_NODES + 15) / 16, 256, 0, stream>>>(h2s, csr_s, offs, counts, dinv, b2, Wo, bo, out);
}

// Round 7
// 207.439 us; speedup vs baseline: 1.8949x; 1.0107x over previous
//
#include <hip/hip_runtime.h>
#include <stdint.h>

#define N_NODES 50000
#define N_EDGES 800000
// D_IN=128, H1=128, H2=64, C=2 — inputs fp32; intermediates bf16 (dinv-prescaled)

typedef __attribute__((ext_vector_type(8))) short short8;     // 8 bf16 (4 VGPRs)
typedef __attribute__((ext_vector_type(4))) float floatx4;    // MFMA acc

// ---------- bf16 helpers ----------
__device__ __forceinline__ float bflo(uint32_t u) { return __uint_as_float(u << 16); }
__device__ __forceinline__ float bfhi(uint32_t u) { return __uint_as_float(u & 0xffff0000u); }
__device__ __forceinline__ unsigned short f2b(float f) {
    uint32_t u = __float_as_uint(f);
    u += 0x7fffu + ((u >> 16) & 1u);   // RNE
    return (unsigned short)(u >> 16);
}

// ---------- 1. prep: zero counts + scan flags, build Wt1/Wt2 bf16 transposes ----------
__global__ void k_prep(const float* __restrict__ W1, const float* __restrict__ W2,
                       unsigned short* __restrict__ Wt1, unsigned short* __restrict__ Wt2,
                       int* __restrict__ counts, unsigned int* __restrict__ flags) {
    int gid = blockIdx.x * 256 + threadIdx.x;
    if (gid < 16384) {                     // Wt1[n][k] = bf16(W1[k][n])
        int k = gid >> 7, n = gid & 127;
        Wt1[n * 128 + k] = f2b(W1[gid]);
    } else if (gid < 24576) {              // Wt2[n][k] = bf16(W2[k][n])
        int j = gid - 16384;
        int k = j >> 6, n = j & 63;
        Wt2[n * 128 + k] = f2b(W2[j]);
    } else if (gid < 24576 + N_NODES) {
        counts[gid - 24576] = 0;
    } else if (gid < 24576 + N_NODES + 256) {
        flags[gid - 24576 - N_NODES] = 0;  // clear 0xAA poison (bit31 would read "ready")
    }
}

// ---------- 2. in-degree count + per-edge rank (atomicAdd return) ----------
__global__ void k_count(const int* __restrict__ dst, int* __restrict__ counts,
                        int* __restrict__ rank) {
    int e = blockIdx.x * 256 + threadIdx.x;
    if (e < N_EDGES) {
        int d = dst[e];
        int r = 0;
        if ((unsigned)d < N_NODES) r = atomicAdd(&counts[d], 1);
        rank[e] = r;
    }
}

// ---------- 3. single-pass exclusive scan (decoupled lookback) + dinv ----------
// 196 blocks; block b publishes aggregate|bit31 (device-scope atomic), then wave 0
// reads predecessors' aggregates with atomic reads (cross-XCD coherent).
__global__ __launch_bounds__(256) void k_scanL(const int* __restrict__ counts,
                                               int* __restrict__ offs,
                                               float* __restrict__ dinv,
                                               unsigned int* __restrict__ flags) {
    int t = threadIdx.x, b = blockIdx.x;
    int idx = b * 256 + t;
    int c = (idx < N_NODES) ? counts[idx] : 0;
    if (idx < N_NODES) dinv[idx] = rsqrtf((float)c + 1.0f);
    int v = c;
    int lane = t & 63, w = t >> 6;
    #pragma unroll
    for (int off = 1; off < 64; off <<= 1) {
        int u = __shfl_up(v, off);
        if (lane >= off) v += u;
    }
    __shared__ int wt[4];
    __shared__ int sh_pre;
    if (lane == 63) wt[w] = v;
    __syncthreads();
    int base = 0;
    for (int j = 0; j < w; j++) base += wt[j];
    if (t == 0) {   // publish block aggregate with ready-flag (no separate fence needed:
                    // data and flag travel in the same 32-bit atomic)
        unsigned int agg = (unsigned int)(wt[0] + wt[1] + wt[2] + wt[3]);
        atomicExch(&flags[b], agg | 0x80000000u);
    }
    if (t < 64) {   // wave-0 lookback over predecessors
        int pre = 0;
        for (int j = lane; j < b; j += 64) {
            unsigned int f;
            do { f = atomicOr(&flags[j], 0u); } while (!(f & 0x80000000u));
            pre += (int)(f & 0x7fffffffu);
        }
        #pragma unroll
        for (int off = 32; off > 0; off >>= 1) pre += __shfl_xor(pre, off);
        if (t == 0) sh_pre = pre;
    }
    __syncthreads();
    if (idx < N_NODES) offs[idx] = sh_pre + base + v - c;
}

// ---------- 4. merged: scatter (blocks 0..3124)  ||  MFMA GEMM1 (blocks 3125..3906)
// scatter: csr_s[offs[d]+rank[e]] = s   (atomic-free, latency-bound)
// gemm1:   h1s[v] = dinv[v] * bf16(x[v]) @ bf16(W1)   (MFMA-bound)
__global__ __launch_bounds__(256) void k_scat_g1(const int* __restrict__ src,
                                                 const int* __restrict__ dst,
                                                 const int* __restrict__ rank,
                                                 const int* __restrict__ offs,
                                                 int* __restrict__ csr_s,
                                                 const float* __restrict__ x,
                                                 const unsigned short* __restrict__ Wt1,
                                                 const float* __restrict__ dinv,
                                                 unsigned short* __restrict__ h1s) {
    __shared__ unsigned short At[64 * 136];   // 17.0 KB (pad 8 bf16: 2-way alias max)
    __shared__ unsigned short Bt[128 * 136];  // 34.0 KB
    if (blockIdx.x < 3125) {                  // ---- scatter branch ----
        int e = blockIdx.x * 256 + threadIdx.x;
        int s = src[e], d = dst[e];
        if ((unsigned)s >= N_NODES || (unsigned)d >= N_NODES) return;
        csr_s[offs[d] + rank[e]] = s;
        return;
    }
    // ---- gemm1 branch ----
    int t = threadIdx.x;
    int row0 = (blockIdx.x - 3125) * 64;
    for (int i = t; i < 2048; i += 256) {     // stage Bt (Wt1 [n][k] bf16)
        int n = i >> 4, kc = (i & 15) * 8;
        *(uint4*)&Bt[n * 136 + kc] = *(const uint4*)(Wt1 + n * 128 + kc);
    }
    for (int i = t; i < 1024; i += 256) {     // stage At: fp32 -> bf16
        int r = i >> 4, kc = (i & 15) * 8;
        int g = row0 + r; if (g >= N_NODES) g = N_NODES - 1;
        const float* p = x + g * 128 + kc;
        float4 a = *(const float4*)p, b = *(const float4*)(p + 4);
        uint4 o;
        o.x = (uint32_t)f2b(a.x) | ((uint32_t)f2b(a.y) << 16);
        o.y = (uint32_t)f2b(a.z) | ((uint32_t)f2b(a.w) << 16);
        o.z = (uint32_t)f2b(b.x) | ((uint32_t)f2b(b.y) << 16);
        o.w = (uint32_t)f2b(b.z) | ((uint32_t)f2b(b.w) << 16);
        *(uint4*)&At[r * 136 + kc] = o;
    }
    __syncthreads();
    int wv = t >> 6, lane = t & 63;
    int m = lane & 15, qd = lane >> 4;
    floatx4 acc[8];
    #pragma unroll
    for (int c = 0; c < 8; c++) acc[c] = (floatx4){0.f, 0.f, 0.f, 0.f};
    const unsigned short* ap = &At[(wv * 16 + m) * 136 + qd * 8];
    const unsigned short* bp = &Bt[m * 136 + qd * 8];
    #pragma unroll
    for (int kk = 0; kk < 4; kk++) {
        short8 af = *(const short8*)(ap + kk * 32);
        #pragma unroll
        for (int c = 0; c < 8; c++) {
            short8 bf = *(const short8*)(bp + c * 16 * 136 + kk * 32);
            acc[c] = __builtin_amdgcn_mfma_f32_16x16x32_bf16(af, bf, acc[c], 0, 0, 0);
        }
    }
    #pragma unroll
    for (int reg = 0; reg < 4; reg++) {       // D[row=qd*4+reg][col=16c+m]
        int g = row0 + wv * 16 + qd * 4 + reg;
        if (g < N_NODES) {
            float di = dinv[g];
            #pragma unroll
            for (int c = 0; c < 8; c++)
                h1s[g * 128 + c * 16 + m] = f2b(di * acc[c][reg]);
        }
    }
}

// ---------- 5. fused agg1 + GEMM2 ----------
// agg: r1[v] = relu(dinv[v]*Σ h1s[N(v)∪{v}] + b1) -> LDS A-tile (16 nodes/block)
// gemm: h2s[v] = dinv[v] * (r1 @ W2) via 1 MFMA col-tile per wave.
__global__ __launch_bounds__(256) void k_agg1g2(const unsigned short* __restrict__ h1s,
                                                const unsigned short* __restrict__ Wt2,
                                                const int* __restrict__ csr_s,
                                                const int* __restrict__ offs,
                                                const int* __restrict__ counts,
                                                const float* __restrict__ dinv,
                                                const float* __restrict__ b1,
                                                unsigned short* __restrict__ h2s) {
    __shared__ unsigned short Bt[64 * 136];   // Wt2 [n=64][k=128] staged
    __shared__ unsigned short At[16 * 136];   // r1 tile [16 rows][128 k]
    int t = threadIdx.x;
    for (int i = t; i < 1024; i += 256) {     // stage Bt2
        int n = i >> 4, kc = (i & 15) * 8;
        *(uint4*)&Bt[n * 136 + kc] = *(const uint4*)(Wt2 + n * 128 + kc);
    }
    int wv = t >> 6, lane = t & 63;
    int q = lane >> 4, l = lane & 15;
    int v0 = blockIdx.x * 16;
    int v = v0 + wv * 4 + q;
    int vv = (v < N_NODES) ? v : N_NODES - 1;
    int start = offs[vv];
    int n = (v < N_NODES) ? counts[vv] : 0;
    const int* cs = csr_s + start;
    int nmax = n;
    nmax = max(nmax, __shfl_xor(nmax, 16));
    nmax = max(nmax, __shfl_xor(nmax, 32));
    float a0, a1, a2, a3, a4, a5, a6, a7;
    {   // self-loop row
        uint4 p = *(const uint4*)(h1s + vv * 128 + l * 8);
        a0 = bflo(p.x); a1 = bfhi(p.x); a2 = bflo(p.y); a3 = bfhi(p.y);
        a4 = bflo(p.z); a5 = bfhi(p.z); a6 = bflo(p.w); a7 = bfhi(p.w);
    }
    for (int base = 0; base < nmax; base += 16) {
        int idx = base + l;
        int e = (idx < n) ? cs[idx] : 0;      // coalesced per quarter
        int mm = nmax - base; if (mm > 16) mm = 16;
        #pragma unroll 4
        for (int i = 0; i < mm; i++) {
            int s = __shfl(e, (q << 4) + i);
            if (base + i < n) {               // uniform within quarter
                uint4 p = *(const uint4*)(h1s + s * 128 + l * 8);
                a0 += bflo(p.x); a1 += bfhi(p.x); a2 += bflo(p.y); a3 += bfhi(p.y);
                a4 += bflo(p.z); a5 += bfhi(p.z); a6 += bflo(p.w); a7 += bfhi(p.w);
            }
        }
    }
    {
        float di = dinv[vv];
        float4 bL = *(const float4*)(b1 + l * 8);
        float4 bH = *(const float4*)(b1 + l * 8 + 4);
        a0 = fmaxf(fmaf(di, a0, bL.x), 0.f); a1 = fmaxf(fmaf(di, a1, bL.y), 0.f);
        a2 = fmaxf(fmaf(di, a2, bL.z), 0.f); a3 = fmaxf(fmaf(di, a3, bL.w), 0.f);
        a4 = fmaxf(fmaf(di, a4, bH.x), 0.f); a5 = fmaxf(fmaf(di, a5, bH.y), 0.f);
        a6 = fmaxf(fmaf(di, a6, bH.z), 0.f); a7 = fmaxf(fmaf(di, a7, bH.w), 0.f);
        uint4 o;
        o.x = (uint32_t)f2b(a0) | ((uint32_t)f2b(a1) << 16);
        o.y = (uint32_t)f2b(a2) | ((uint32_t)f2b(a3) << 16);
        o.z = (uint32_t)f2b(a4) | ((uint32_t)f2b(a5) << 16);
        o.w = (uint32_t)f2b(a6) | ((uint32_t)f2b(a7) << 16);
        *(uint4*)&At[(wv * 4 + q) * 136 + l * 8] = o;   // r1 tile row
    }
    __syncthreads();
    // MFMA: wave wv -> col-tile wv (cols 16wv..16wv+15)
    int m = lane & 15, qd = lane >> 4;
    floatx4 acc = (floatx4){0.f, 0.f, 0.f, 0.f};
    const unsigned short* ap = &At[m * 136 + qd * 8];
    const unsigned short* bp = &Bt[(wv * 16 + m) * 136 + qd * 8];
    #pragma unroll
    for (int kk = 0; kk < 4; kk++) {
        short8 af = *(const short8*)(ap + kk * 32);
        short8 bf = *(const short8*)(bp + kk * 32);
        acc = __builtin_amdgcn_mfma_f32_16x16x32_bf16(af, bf, acc, 0, 0, 0);
    }
    #pragma unroll
    for (int reg = 0; reg < 4; reg++) {
        int g = v0 + qd * 4 + reg;
        if (g < N_NODES) {
            float di = dinv[g];
            h2s[g * 64 + wv * 16 + m] = f2b(di * acc[reg]);
        }
    }
}

// ---------- 6. agg2 + head: h3 = relu(dinv*Σ h2s + b2); out = log_softmax(h3@Wo+bo)
__global__ __launch_bounds__(256) void k_agg2(const unsigned short* __restrict__ h2s,
                                              const int* __restrict__ csr_s,
                                              const int* __restrict__ offs,
                                              const int* __restrict__ counts,
                                              const float* __restrict__ dinv,
                                              const float* __restrict__ b2,
                                              const float* __restrict__ Wo,
                                              const float* __restrict__ bo,
                                              float* __restrict__ out) {
    int wave = (blockIdx.x * 256 + threadIdx.x) >> 6;
    int lane = threadIdx.x & 63;
    int q = lane >> 4, l = lane & 15;
    int v = wave * 4 + q;
    bool valid = v < N_NODES;
    int vv = valid ? v : N_NODES - 1;
    int start = offs[vv];
    int n = valid ? counts[vv] : 0;
    const int* cs = csr_s + start;
    int nmax = n;
    nmax = max(nmax, __shfl_xor(nmax, 16));
    nmax = max(nmax, __shfl_xor(nmax, 32));
    float a0, a1, a2, a3;
    {
        uint2 p = *(const uint2*)(h2s + vv * 64 + l * 4);
        a0 = bflo(p.x); a1 = bfhi(p.x); a2 = bflo(p.y); a3 = bfhi(p.y);
    }
    for (int base = 0; base < nmax; base += 16) {
        int idx = base + l;
        int e = (idx < n) ? cs[idx] : 0;
        int mm = nmax - base; if (mm > 16) mm = 16;
        #pragma unroll 4
        for (int i = 0; i < mm; i++) {
            int s = __shfl(e, (q << 4) + i);
            if (base + i < n) {
                uint2 p = *(const uint2*)(h2s + s * 64 + l * 4);
                a0 += bflo(p.x); a1 += bfhi(p.x); a2 += bflo(p.y); a3 += bfhi(p.y);
            }
        }
    }
    float di = valid ? dinv[vv] : 0.f;
    float4 bb = *(const float4*)(b2 + l * 4);
    a0 = fmaxf(fmaf(di, a0, bb.x), 0.f);
    a1 = fmaxf(fmaf(di, a1, bb.y), 0.f);
    a2 = fmaxf(fmaf(di, a2, bb.z), 0.f);
    a3 = fmaxf(fmaf(di, a3, bb.w), 0.f);
    float4 w01 = *(const float4*)(Wo + l * 8);
    float4 w23 = *(const float4*)(Wo + l * 8 + 4);
    float l0 = a0 * w01.x + a1 * w01.z + a2 * w23.x + a3 * w23.z;
    float l1 = a0 * w01.y + a1 * w01.w + a2 * w23.y + a3 * w23.w;
    #pragma unroll
    for (int off = 8; off > 0; off >>= 1) {
        l0 += __shfl_xor(l0, off);
        l1 += __shfl_xor(l1, off);
    }
    if (l == 0 && valid) {
        float2 bof = *(const float2*)bo;
        l0 += bof.x; l1 += bof.y;
        float m = fmaxf(l0, l1);
        float ls = m + __logf(__expf(l0 - m) + __expf(l1 - m));
        *(float2*)(out + v * 2) = make_float2(l0 - ls, l1 - ls);
    }
}

extern "C" void kernel_launch(void* const* d_in, const int* in_sizes, int n_in,
                              void* d_out, int out_size, void* d_ws, size_t ws_size,
                              hipStream_t stream) {
    const float* x  = (const float*)d_in[0];
    const int* ei   = (const int*)d_in[1];
    const float* W1 = (const float*)d_in[2];
    const float* b1 = (const float*)d_in[3];
    const float* W2 = (const float*)d_in[4];
    const float* b2 = (const float*)d_in[5];
    const float* Wo = (const float*)d_in[6];
    const float* bo = (const float*)d_in[7];
    float* out      = (float*)d_out;
    const int* src = ei;             // edge_index[0]
    const int* dst = ei + N_EDGES;   // edge_index[1]

    char* w = (char*)d_ws;
    int*   counts = (int*)(w + 0);            // 200 KB
    int*   offs   = (int*)(w + 200704);       // 200 KB
    float* dinv   = (float*)(w + 401408);     // 200 KB
    unsigned int* flags = (unsigned int*)(w + 602112);  // 1 KB (scan lookback)
    int*   rank   = (int*)(w + 603136);       // 3.2 MB
    int*   csr_s  = (int*)(w + 3803136);      // 3.2 MB
    unsigned short* Wt1 = (unsigned short*)(w + 7003136);  // 32 KB  [n=128][k=128]
    unsigned short* Wt2 = (unsigned short*)(w + 7035904);  // 16 KB  [n=64][k=128]
    unsigned short* h1s = (unsigned short*)(w + 7052800);  // 12.8 MB
    unsigned short* h2s = (unsigned short*)(w + 19852800); // 6.4 MB
    // total ws usage: ~26.3 MB

    k_prep   <<<293, 256, 0, stream>>>(W1, W2, Wt1, Wt2, counts, flags);
    k_count  <<<3125, 256, 0, stream>>>(dst, counts, rank);
    k_scanL  <<<196, 256, 0, stream>>>(counts, offs, dinv, flags);
    k_scat_g1<<<3907, 256, 0, stream>>>(src, dst, rank, offs, csr_s, x, Wt1, dinv, h1s);
    k_agg1g2 <<<3125, 256, 0, stream>>>(h1s, Wt2, csr_s, offs, counts, dinv, b1, h2s);
    k_agg2   <<<3125, 256, 0, stream>>>(h2s, csr_s, offs, counts, dinv, b2, Wo, bo, out);
}